// Round 1
// baseline (1124.962 us; speedup 1.0000x reference)
//
#include <hip/hip_runtime.h>

// ResidualMambaTokenStage: patch-embed conv (as GEMM) + ch-LN, then 2x
// (LN -> in_proj -> causal dwconv1d+silu -> x_proj -> dt/softplus ->
//  selective scan -> gate -> out_proj + residual).
// B=4, L=1024 tokens, DM=512, D_INNER=1024, D_STATE=16, DT_RANK=32.
// Strategy: bf16 MFMA for all GEMMs (threshold 9.7e-2 allows it); fused
// scan kernel that computes delta on the fly (no dA/dBu materialization).

#define BB   4
#define LL   1024        // tokens per batch (32x32)
#define MTOK 4096        // B*L
#define DM_  512
#define DIN  1024
#define DST  16
#define DTR  32
#define KPATCH 768       // 3*16*16

typedef unsigned short u16;
typedef __attribute__((ext_vector_type(8))) short bf16x8_t;
typedef __attribute__((ext_vector_type(4))) float floatx4_t;

__device__ inline u16 f2bf(float f) {
    unsigned int u = __float_as_uint(f);
    unsigned int r = (u + 0x7FFFu + ((u >> 16) & 1u)) >> 16;   // RNE
    return (u16)r;
}
__device__ inline float bf2f(u16 h) {
    return __uint_as_float(((unsigned int)h) << 16);
}

// ---------------------------------------------------------------- weights
// wPatch[512][768], wIn[2][2048][512], wXpPad[2][128][1024] (rows>=64 zero),
// wOut[2][512][1024] -- all [n][k] row-major, k contiguous (source layouts
// are already n-major so this is a pure elementwise convert).
__global__ __launch_bounds__(256) void convert_weights(
    const float* __restrict__ conv_w, const float* __restrict__ in_proj_w,
    const float* __restrict__ x_proj_w, const float* __restrict__ out_proj_w,
    u16* __restrict__ wPatch, u16* __restrict__ wIn,
    u16* __restrict__ wXp, u16* __restrict__ wOut)
{
    int g = blockIdx.x * 256 + threadIdx.x;
    const int N0 = 393216;            // conv_w
    const int N1 = N0 + 2097152;      // in_proj
    const int N2 = N1 + 262144;       // x_proj padded out
    const int N3 = N2 + 1048576;      // out_proj
    if (g < N0) {
        wPatch[g] = f2bf(conv_w[g]);
    } else if (g < N1) {
        int o = g - N0; wIn[o] = f2bf(in_proj_w[o]);
    } else if (g < N2) {
        int o = g - N1;
        int blk = o >> 17;            // 131072 per block
        int rem = o & 131071;
        int n = rem >> 10, k = rem & 1023;
        wXp[o] = (n < 64) ? f2bf(x_proj_w[blk * 65536 + n * 1024 + k]) : (u16)0;
    } else if (g < N3) {
        int o = g - N2; wOut[o] = f2bf(out_proj_w[o]);
    }
}

// ------------------------------------------------------------- patch im2col
// A_patch[m=4096][k=768] bf16, k = c*256 + py*16 + px
__global__ __launch_bounds__(256) void build_patches(
    const float* __restrict__ x, u16* __restrict__ Ap)
{
    int g = blockIdx.x * 256 + threadIdx.x;          // 4096*768 threads
    int m = g / KPATCH, k = g % KPATCH;
    int b = m >> 10, l = m & 1023, hp = l >> 5, wp = l & 31;
    int c = k >> 8, rem = k & 255, py = rem >> 4, px = rem & 15;
    float v = x[(((size_t)(b * 3 + c)) * 512 + hp * 16 + py) * 512 + wp * 16 + px];
    Ap[g] = f2bf(v);
}

// ------------------------------------------------------------------- GEMM
// C[M][N] = A[M][K] * Bt[N][K]^T  (bf16 in, f32 out). 128x128 tile, 4 waves,
// BK=32, mfma_f32_16x16x32_bf16. EPI: 0 none, 1 +bias[col], 2 +res[m][n].
template<int EPI>
__global__ __launch_bounds__(256, 2) void gemm_bt(
    const u16* __restrict__ A, const u16* __restrict__ Bt,
    float* __restrict__ C, const float* __restrict__ bias,
    const float* __restrict__ res, int M, int N, int K)
{
    __shared__ short As[128 * 40];    // rows padded 32->40 (2-way bank alias, free)
    __shared__ short Bs[128 * 40];
    const int tid  = threadIdx.x;
    const int lane = tid & 63;
    const int wid  = tid >> 6;
    const int quad = lane >> 4;
    const int l16  = lane & 15;
    const int wm = wid >> 1, wn = wid & 1;
    const int m0 = blockIdx.y * 128, n0 = blockIdx.x * 128;

    floatx4_t acc[4][4] = {};

    const int c0 = tid, c1 = tid + 256;
    const int r0 = c0 >> 2, o0 = (c0 & 3) * 8;
    const int r1 = c1 >> 2, o1 = (c1 & 3) * 8;

    for (int kk = 0; kk < K; kk += 32) {
        *(bf16x8_t*)&As[r0 * 40 + o0] = *(const bf16x8_t*)&A[(size_t)(m0 + r0) * K + kk + o0];
        *(bf16x8_t*)&As[r1 * 40 + o1] = *(const bf16x8_t*)&A[(size_t)(m0 + r1) * K + kk + o1];
        *(bf16x8_t*)&Bs[r0 * 40 + o0] = *(const bf16x8_t*)&Bt[(size_t)(n0 + r0) * K + kk + o0];
        *(bf16x8_t*)&Bs[r1 * 40 + o1] = *(const bf16x8_t*)&Bt[(size_t)(n0 + r1) * K + kk + o1];
        __syncthreads();
        bf16x8_t af[4], bfr[4];
#pragma unroll
        for (int t = 0; t < 4; t++)
            af[t] = *(const bf16x8_t*)&As[(wm * 64 + t * 16 + l16) * 40 + quad * 8];
#pragma unroll
        for (int t = 0; t < 4; t++)
            bfr[t] = *(const bf16x8_t*)&Bs[(wn * 64 + t * 16 + l16) * 40 + quad * 8];
#pragma unroll
        for (int tm = 0; tm < 4; tm++)
#pragma unroll
            for (int tn = 0; tn < 4; tn++)
                acc[tm][tn] = __builtin_amdgcn_mfma_f32_16x16x32_bf16(
                    af[tm], bfr[tn], acc[tm][tn], 0, 0, 0);
        __syncthreads();
    }
#pragma unroll
    for (int tm = 0; tm < 4; tm++) {
#pragma unroll
        for (int r = 0; r < 4; r++) {
            int gr = m0 + wm * 64 + tm * 16 + quad * 4 + r;
#pragma unroll
            for (int tn = 0; tn < 4; tn++) {
                int gc = n0 + wn * 64 + tn * 16 + l16;
                float v = acc[tm][tn][r];
                if (EPI == 1) v += bias[gc];
                if (EPI == 2) v += res[(size_t)gr * N + gc];
                C[(size_t)gr * N + gc] = v;
            }
        }
    }
}

// --------------------------------------------------------------------- LN
// One wave per token (512 channels, 8/lane). BF16OUT: write bf16 else f32.
template<bool BF16OUT>
__global__ __launch_bounds__(256) void ln_kernel(
    const float* __restrict__ in, void* __restrict__ out,
    const float* __restrict__ g, const float* __restrict__ b)
{
    int token = blockIdx.x * 4 + (threadIdx.x >> 6);
    int lane  = threadIdx.x & 63;
    const float* row = in + (size_t)token * DM_;
    float v[8], s = 0.f, q = 0.f;
#pragma unroll
    for (int j = 0; j < 8; j++) {
        v[j] = row[lane + j * 64];
        s += v[j]; q = fmaf(v[j], v[j], q);
    }
#pragma unroll
    for (int off = 32; off >= 1; off >>= 1) {
        s += __shfl_xor(s, off);
        q += __shfl_xor(q, off);
    }
    float mean = s * (1.f / DM_);
    float var  = q * (1.f / DM_) - mean * mean;
    float inv  = rsqrtf(var + 1e-5f);
#pragma unroll
    for (int j = 0; j < 8; j++) {
        int idx = lane + j * 64;
        float o = (v[j] - mean) * inv * g[idx] + b[idx];
        if (BF16OUT) ((u16*)out)[(size_t)token * DM_ + idx] = f2bf(o);
        else         ((float*)out)[(size_t)token * DM_ + idx] = o;
    }
}

// ----------------------------------------------------- causal dwconv1d+silu
// u[m][d] = silu(sum_j xin[b, l-3+j, d]*w[d][j] + cb[d]); xin = xz[:, 0:1024]
__global__ __launch_bounds__(256) void conv1d_silu(
    const float* __restrict__ xz, const float* __restrict__ w,
    const float* __restrict__ cb, u16* __restrict__ u_bf)
{
    int g = blockIdx.x * 256 + threadIdx.x;      // 4096*1024
    int d = g & 1023, m = g >> 10, l = m & 1023;
    float acc = cb[d];
#pragma unroll
    for (int j = 0; j < 4; j++) {
        int lj = l + j - 3;
        if (lj >= 0)
            acc = fmaf(xz[(size_t)(m + j - 3) * 2048 + d], w[d * 4 + j], acc);
    }
    float uu = acc / (1.f + expf(-acc));
    u_bf[g] = f2bf(uu);
}

// ------------------------------------------------------------ fused scan
// Block = (d-tile of 16) x (batch). 256 thr = 16 d x 16 s. Per 16-step
// chunk: stage xdbl rows (dt|B|C), u, silu(z); compute delta (dt_proj +
// softplus) cooperatively; then sequential scan with h in registers and
// 16-lane shfl reduction over states. Emits y_bf16 = (scan + u*Dp)*silu(z).
__global__ __launch_bounds__(256) void scan_kernel(
    const float* __restrict__ xdbl, const u16* __restrict__ u_bf,
    const float* __restrict__ xz, const float* __restrict__ dpw,
    const float* __restrict__ dpb, const float* __restrict__ alog,
    const float* __restrict__ Dp, u16* __restrict__ y_bf)
{
    __shared__ float s_xdbl[16][68];
    __shared__ float s_u[16][17];
    __shared__ float s_sz[16][17];
    __shared__ float s_delta[16][17];
    __shared__ float s_dpw[16][33];
    __shared__ float s_dpb[16];

    const int tid = threadIdx.x;
    const int d0 = blockIdx.x * 16;
    const int b  = blockIdx.y;
    const int sc_di = tid >> 4, sc_s = tid & 15;     // scan mapping
    const int st_li = tid >> 4, st_dd = tid & 15;    // staging mapping

    const int dg = d0 + sc_di;
    const float a_neg   = -expf(alog[dg * 16 + sc_s]);
    const float dp_skip = Dp[dg];

    for (int idx = tid; idx < 512; idx += 256) {
        int di = idx >> 5, r = idx & 31;
        s_dpw[di][r] = dpw[(d0 + di) * 32 + r];
    }
    if (tid < 16) s_dpb[tid] = dpb[d0 + tid];

    const int base_m = b * LL;
    float h = 0.f;

    for (int l0 = 0; l0 < LL; l0 += 16) {
        __syncthreads();
        for (int idx = tid; idx < 1024; idx += 256) {
            int li = idx >> 6, c = idx & 63;
            s_xdbl[li][c] = xdbl[(size_t)(base_m + l0 + li) * 128 + c];
        }
        {
            float uu = bf2f(u_bf[(size_t)(base_m + l0 + st_li) * 1024 + d0 + st_dd]);
            s_u[st_li][st_dd] = uu;
            float zz = xz[(size_t)(base_m + l0 + st_li) * 2048 + 1024 + d0 + st_dd];
            s_sz[st_li][st_dd] = zz / (1.f + expf(-zz));
        }
        __syncthreads();
        {   // delta = softplus(dt @ dpw^T + dpb), dt = xdbl[:, 0:32]
            float acc = s_dpb[st_dd];
#pragma unroll
            for (int r = 0; r < 32; r++)
                acc = fmaf(s_xdbl[st_li][r], s_dpw[st_dd][r], acc);
            s_delta[st_li][st_dd] = (acc > 20.f) ? acc : log1pf(expf(acc));
        }
        __syncthreads();
#pragma unroll
        for (int li = 0; li < 16; li++) {
            float dl = s_delta[li][sc_di];
            float uu = s_u[li][sc_di];
            float bb = s_xdbl[li][32 + sc_s];
            float cc = s_xdbl[li][48 + sc_s];
            float dA = expf(dl * a_neg);
            h = fmaf(dA, h, dl * bb * uu);
            float yp = h * cc;
            yp += __shfl_xor(yp, 1, 16);
            yp += __shfl_xor(yp, 2, 16);
            yp += __shfl_xor(yp, 4, 16);
            yp += __shfl_xor(yp, 8, 16);
            if (sc_s == 0) {
                float y = (yp + uu * dp_skip) * s_sz[li][sc_di];
                y_bf[(size_t)(base_m + l0 + li) * 1024 + d0 + sc_di] = f2bf(y);
            }
        }
    }
}

// ---------------------------------------------------------------- launcher
extern "C" void kernel_launch(void* const* d_in, const int* in_sizes, int n_in,
                              void* d_out, int out_size, void* d_ws, size_t ws_size,
                              hipStream_t stream)
{
    const float* x         = (const float*)d_in[0];
    const float* conv_w    = (const float*)d_in[1];
    const float* conv_b    = (const float*)d_in[2];
    const float* pe_g      = (const float*)d_in[3];
    const float* pe_b      = (const float*)d_in[4];
    const float* ln_g      = (const float*)d_in[5];
    const float* ln_b      = (const float*)d_in[6];
    const float* in_proj_w = (const float*)d_in[7];
    const float* c1d_w     = (const float*)d_in[8];
    const float* c1d_b     = (const float*)d_in[9];
    const float* x_proj_w  = (const float*)d_in[10];
    const float* dt_proj_w = (const float*)d_in[11];
    const float* dt_proj_b = (const float*)d_in[12];
    const float* A_log     = (const float*)d_in[13];
    const float* Dp        = (const float*)d_in[14];
    const float* out_proj_w= (const float*)d_in[15];

    char* ws = (char*)d_ws;
    // ws layout (72.6 MB total). A_patch & xe alias inside the xz slab
    // (dead before xz is written).
    float* xz      = (float*)(ws + 0);             // 33,554,432 B
    u16*   A_patch = (u16*)  (ws + 0);             //  6,291,456 B (phase 1)
    float* xe      = (float*)(ws + 6291456);       //  8,388,608 B (phase 1)
    float* tokens  = (float*)(ws + 33554432);      //  8,388,608
    u16*   t_bf    = (u16*)  (ws + 41943040);      //  4,194,304
    u16*   u_bf    = (u16*)  (ws + 46137344);      //  8,388,608
    float* xdbl    = (float*)(ws + 54525952);      //  2,097,152
    u16*   y_bf    = (u16*)  (ws + 56623104);      //  8,388,608
    u16*   wPatch  = (u16*)  (ws + 65011712);      //    786,432
    u16*   wIn     = (u16*)  (ws + 65798144);      //  4,194,304
    u16*   wXp     = (u16*)  (ws + 69992448);      //    524,288
    u16*   wOut    = (u16*)  (ws + 70516736);      //  2,097,152

    dim3 blk(256);

    convert_weights<<<14848, blk, 0, stream>>>(conv_w, in_proj_w, x_proj_w,
                                               out_proj_w, wPatch, wIn, wXp, wOut);
    build_patches<<<12288, blk, 0, stream>>>(x, A_patch);
    // patch-embed GEMM + conv bias: [4096 x 768] x [512 x 768]^T
    gemm_bt<1><<<dim3(4, 32), blk, 0, stream>>>(A_patch, wPatch, xe, conv_b,
                                                nullptr, MTOK, DM_, KPATCH);
    // channel-LN (= per-token LN over DM) with pe_g/pe_b -> tokens f32
    ln_kernel<false><<<1024, blk, 0, stream>>>(xe, tokens, pe_g, pe_b);

    for (int i = 0; i < 2; i++) {
        ln_kernel<true><<<1024, blk, 0, stream>>>(tokens, t_bf,
                                                  ln_g + i * DM_, ln_b + i * DM_);
        // in_proj: [4096 x 512] x [2048 x 512]^T -> xz
        gemm_bt<0><<<dim3(16, 32), blk, 0, stream>>>(t_bf, wIn + i * 1048576, xz,
                                                     nullptr, nullptr, MTOK, 2048, DM_);
        conv1d_silu<<<16384, blk, 0, stream>>>(xz, c1d_w + i * 4096,
                                               c1d_b + i * 1024, u_bf);
        // x_proj: [4096 x 1024] x [128 x 1024]^T -> xdbl (cols 64..127 zero)
        gemm_bt<0><<<dim3(1, 32), blk, 0, stream>>>(u_bf, wXp + i * 131072, xdbl,
                                                    nullptr, nullptr, MTOK, 128, DIN);
        scan_kernel<<<dim3(64, 4), blk, 0, stream>>>(xdbl, u_bf, xz,
                                                     dt_proj_w + i * 32768,
                                                     dt_proj_b + i * 1024,
                                                     A_log + i * 16384,
                                                     Dp + i * 1024, y_bf);
        // out_proj + residual: [4096 x 1024] x [512 x 1024]^T + tokens
        float* dst = (i == 1) ? (float*)d_out : tokens;
        gemm_bt<2><<<dim3(4, 32), blk, 0, stream>>>(y_bf, wOut + i * 524288, dst,
                                                    nullptr, tokens, MTOK, DM_, DIN);
    }
}

// Round 2
// 598.785 us; speedup vs baseline: 1.8787x; 1.8787x over previous
//
#include <hip/hip_runtime.h>

// ResidualMambaTokenStage: patch-embed conv (as GEMM) + ch-LN, then 2x
// (LN -> in_proj -> causal dwconv1d+silu -> x_proj -> dt/softplus ->
//  selective scan -> gate -> out_proj + residual).
// R2: chunk-parallel selective scan (16 chunks of 64 over L), delta via
// MFMA GEMM w/ softplus epilogue, in_proj split so z-half is silu'd bf16.

#define BB   4
#define LL   1024
#define MTOK 4096
#define DM_  512
#define DIN  1024
#define DST  16
#define DTR  32
#define KPATCH 768
#define LCH  64          // chunk length
#define NCH  16          // chunks per sequence
#define NBDS 65536       // B * DIN * DST sequences

typedef unsigned short u16;
typedef __attribute__((ext_vector_type(8))) short bf16x8_t;
typedef __attribute__((ext_vector_type(4))) float floatx4_t;

__device__ inline u16 f2bf(float f) {
    unsigned int u = __float_as_uint(f);
    unsigned int r = (u + 0x7FFFu + ((u >> 16) & 1u)) >> 16;   // RNE
    return (u16)r;
}
__device__ inline float bf2f(u16 h) {
    return __uint_as_float(((unsigned int)h) << 16);
}

// ---------------------------------------------------------------- weights
__global__ __launch_bounds__(256) void convert_weights(
    const float* __restrict__ conv_w, const float* __restrict__ in_proj_w,
    const float* __restrict__ x_proj_w, const float* __restrict__ out_proj_w,
    const float* __restrict__ dt_proj_w,
    u16* __restrict__ wPatch, u16* __restrict__ wIn,
    u16* __restrict__ wXp, u16* __restrict__ wOut, u16* __restrict__ wDt)
{
    int g = blockIdx.x * 256 + threadIdx.x;
    const int N0 = 393216;            // conv_w 512*768
    const int N1 = N0 + 2097152;      // in_proj 2*2048*512
    const int N2 = N1 + 262144;      // x_proj padded 2*128*1024
    const int N3 = N2 + 1048576;     // out_proj 2*512*1024
    const int N4 = N3 + 65536;       // dt_proj_w 2*1024*32
    if (g < N0) {
        wPatch[g] = f2bf(conv_w[g]);
    } else if (g < N1) {
        int o = g - N0; wIn[o] = f2bf(in_proj_w[o]);
    } else if (g < N2) {
        int o = g - N1;
        int blk = o >> 17, rem = o & 131071;
        int n = rem >> 10, k = rem & 1023;
        wXp[o] = (n < 64) ? f2bf(x_proj_w[blk * 65536 + n * 1024 + k]) : (u16)0;
    } else if (g < N3) {
        int o = g - N2; wOut[o] = f2bf(out_proj_w[o]);
    } else if (g < N4) {
        int o = g - N3; wDt[o] = f2bf(dt_proj_w[o]);
    }
}

// ------------------------------------------------------------- patch im2col
__global__ __launch_bounds__(256) void build_patches(
    const float* __restrict__ x, u16* __restrict__ Ap)
{
    int g = blockIdx.x * 256 + threadIdx.x;
    int m = g / KPATCH, k = g % KPATCH;
    int b = m >> 10, l = m & 1023, hp = l >> 5, wp = l & 31;
    int c = k >> 8, rem = k & 255, py = rem >> 4, px = rem & 15;
    float v = x[(((size_t)(b * 3 + c)) * 512 + hp * 16 + py) * 512 + wp * 16 + px];
    Ap[g] = f2bf(v);
}

// ------------------------------------------------------------------- GEMM
// C[M][N] = A[M][K] * Bt[N][K]^T. EPI: 0 none, 1 +bias, 2 +res,
// 3 softplus(v+bias) f32 out, 4 silu(v) bf16 out.
template<int EPI>
__global__ __launch_bounds__(256, 2) void gemm_bt(
    const u16* __restrict__ A, const u16* __restrict__ Bt,
    float* __restrict__ C, const float* __restrict__ bias,
    const float* __restrict__ res, int M, int N, int K)
{
    __shared__ short As[128 * 40];
    __shared__ short Bs[128 * 40];
    const int tid  = threadIdx.x;
    const int lane = tid & 63;
    const int wid  = tid >> 6;
    const int quad = lane >> 4;
    const int l16  = lane & 15;
    const int wm = wid >> 1, wn = wid & 1;
    const int m0 = blockIdx.y * 128, n0 = blockIdx.x * 128;

    floatx4_t acc[4][4] = {};

    const int c0 = tid, c1 = tid + 256;
    const int r0 = c0 >> 2, o0 = (c0 & 3) * 8;
    const int r1 = c1 >> 2, o1 = (c1 & 3) * 8;

    for (int kk = 0; kk < K; kk += 32) {
        *(bf16x8_t*)&As[r0 * 40 + o0] = *(const bf16x8_t*)&A[(size_t)(m0 + r0) * K + kk + o0];
        *(bf16x8_t*)&As[r1 * 40 + o1] = *(const bf16x8_t*)&A[(size_t)(m0 + r1) * K + kk + o1];
        *(bf16x8_t*)&Bs[r0 * 40 + o0] = *(const bf16x8_t*)&Bt[(size_t)(n0 + r0) * K + kk + o0];
        *(bf16x8_t*)&Bs[r1 * 40 + o1] = *(const bf16x8_t*)&Bt[(size_t)(n0 + r1) * K + kk + o1];
        __syncthreads();
        bf16x8_t af[4], bfr[4];
#pragma unroll
        for (int t = 0; t < 4; t++)
            af[t] = *(const bf16x8_t*)&As[(wm * 64 + t * 16 + l16) * 40 + quad * 8];
#pragma unroll
        for (int t = 0; t < 4; t++)
            bfr[t] = *(const bf16x8_t*)&Bs[(wn * 64 + t * 16 + l16) * 40 + quad * 8];
#pragma unroll
        for (int tm = 0; tm < 4; tm++)
#pragma unroll
            for (int tn = 0; tn < 4; tn++)
                acc[tm][tn] = __builtin_amdgcn_mfma_f32_16x16x32_bf16(
                    af[tm], bfr[tn], acc[tm][tn], 0, 0, 0);
        __syncthreads();
    }
#pragma unroll
    for (int tm = 0; tm < 4; tm++) {
#pragma unroll
        for (int r = 0; r < 4; r++) {
            int gr = m0 + wm * 64 + tm * 16 + quad * 4 + r;
#pragma unroll
            for (int tn = 0; tn < 4; tn++) {
                int gc = n0 + wn * 64 + tn * 16 + l16;
                float v = acc[tm][tn][r];
                if (EPI == 1) v += bias[gc];
                if (EPI == 2) v += res[(size_t)gr * N + gc];
                if (EPI == 3) {
                    v += bias[gc];
                    v = (v > 20.f) ? v : log1pf(__expf(v));
                }
                if (EPI == 4) {
                    float sv = v / (1.f + __expf(-v));
                    ((u16*)C)[(size_t)gr * N + gc] = f2bf(sv);
                } else {
                    C[(size_t)gr * N + gc] = v;
                }
            }
        }
    }
}

// --------------------------------------------------------------------- LN
template<bool BF16OUT>
__global__ __launch_bounds__(256) void ln_kernel(
    const float* __restrict__ in, void* __restrict__ out,
    const float* __restrict__ g, const float* __restrict__ b)
{
    int token = blockIdx.x * 4 + (threadIdx.x >> 6);
    int lane  = threadIdx.x & 63;
    const float* row = in + (size_t)token * DM_;
    float v[8], s = 0.f, q = 0.f;
#pragma unroll
    for (int j = 0; j < 8; j++) {
        v[j] = row[lane + j * 64];
        s += v[j]; q = fmaf(v[j], v[j], q);
    }
#pragma unroll
    for (int off = 32; off >= 1; off >>= 1) {
        s += __shfl_xor(s, off);
        q += __shfl_xor(q, off);
    }
    float mean = s * (1.f / DM_);
    float var  = q * (1.f / DM_) - mean * mean;
    float inv  = rsqrtf(var + 1e-5f);
#pragma unroll
    for (int j = 0; j < 8; j++) {
        int idx = lane + j * 64;
        float o = (v[j] - mean) * inv * g[idx] + b[idx];
        if (BF16OUT) ((u16*)out)[(size_t)token * DM_ + idx] = f2bf(o);
        else         ((float*)out)[(size_t)token * DM_ + idx] = o;
    }
}

// ----------------------------------------------------- causal dwconv1d+silu
// xz_x is [4096][1024] f32 (the x-half of in_proj output).
__global__ __launch_bounds__(256) void conv1d_silu(
    const float* __restrict__ xz_x, const float* __restrict__ w,
    const float* __restrict__ cb, u16* __restrict__ u_bf)
{
    int g = blockIdx.x * 256 + threadIdx.x;      // 4096*1024
    int d = g & 1023, m = g >> 10, l = m & 1023;
    float acc = cb[d];
#pragma unroll
    for (int j = 0; j < 4; j++) {
        int lj = l + j - 3;
        if (lj >= 0)
            acc = fmaf(xz_x[(size_t)(m + j - 3) * 1024 + d], w[d * 4 + j], acc);
    }
    float uu = acc / (1.f + __expf(-acc));
    u_bf[g] = f2bf(uu);
}

// ------------------------------------------------------------ dt extraction
__global__ __launch_bounds__(256) void extract_dt(
    const float* __restrict__ xdbl, u16* __restrict__ dt_bf)
{
    int g = blockIdx.x * 256 + threadIdx.x;      // 4096*32
    int m = g >> 5, c = g & 31;
    dt_bf[g] = f2bf(xdbl[(size_t)m * 128 + c]);
}

// ------------------------------------------------- chunk-parallel scan: P1
// Grid (64 d-tiles, 4 batches, 16 chunks); 256 thr = 16 d x 16 s.
// Each thread: 64-step affine summary (P,Q) of h <- a*h + x over its chunk.
__global__ __launch_bounds__(256) void scan_part1(
    const float* __restrict__ delta, const u16* __restrict__ u_bf,
    const float* __restrict__ xdbl, const float* __restrict__ alog,
    float2* __restrict__ summ)
{
    __shared__ float s_d[LCH][16], s_u[LCH][16], s_B[LCH][16];
    const int tid = threadIdx.x;
    const int d0 = blockIdx.x * 16, b = blockIdx.y, ch = blockIdx.z;
    const int di = tid >> 4, s = tid & 15;
    const int base_m = b * LL + ch * LCH;

    for (int e = tid; e < LCH * 16; e += 256) {
        int li = e >> 4, c = e & 15;
        size_t m = base_m + li;
        s_d[li][c] = delta[m * 1024 + d0 + c];
        s_u[li][c] = bf2f(u_bf[m * 1024 + d0 + c]);
        s_B[li][c] = xdbl[m * 128 + 32 + c];
    }
    const float aneg = -__expf(alog[(d0 + di) * 16 + s]);
    __syncthreads();

    float P = 1.f, Q = 0.f;
#pragma unroll
    for (int j = 0; j < LCH; j++) {
        float dl = s_d[j][di];
        float a  = __expf(dl * aneg);
        float x  = dl * s_B[j][s] * s_u[j][di];
        P *= a;
        Q = fmaf(a, Q, x);
    }
    summ[(size_t)ch * NBDS + (b * 1024 + d0) * 16 + tid] = make_float2(P, Q);
}

// ------------------------------------------------- carry scan over chunks
__global__ __launch_bounds__(256) void scan_carry(
    const float2* __restrict__ summ, float* __restrict__ hinit)
{
    int bds = blockIdx.x * 256 + threadIdx.x;    // 65536
    float2 pq[NCH];
#pragma unroll
    for (int c = 0; c < NCH; c++) pq[c] = summ[(size_t)c * NBDS + bds];
    float h = 0.f;
#pragma unroll
    for (int c = 0; c < NCH; c++) {
        hinit[(size_t)c * NBDS + bds] = h;
        h = fmaf(pq[c].x, h, pq[c].y);
    }
}

// ------------------------------------------------- chunk-parallel scan: P2
// Replay chunk with correct h0; reduce over s (shfl width 16); gate; emit y.
__global__ __launch_bounds__(256) void scan_part2(
    const float* __restrict__ delta, const u16* __restrict__ u_bf,
    const float* __restrict__ xdbl, const u16* __restrict__ g_bf,
    const float* __restrict__ alog, const float* __restrict__ Dp,
    const float* __restrict__ hinit, u16* __restrict__ y_bf)
{
    __shared__ float s_d[LCH][16], s_u[LCH][16], s_B[LCH][16];
    __shared__ float s_C[LCH][16], s_g[LCH][16];
    const int tid = threadIdx.x;
    const int d0 = blockIdx.x * 16, b = blockIdx.y, ch = blockIdx.z;
    const int di = tid >> 4, s = tid & 15;
    const int base_m = b * LL + ch * LCH;

    for (int e = tid; e < LCH * 16; e += 256) {
        int li = e >> 4, c = e & 15;
        size_t m = base_m + li;
        s_d[li][c] = delta[m * 1024 + d0 + c];
        s_u[li][c] = bf2f(u_bf[m * 1024 + d0 + c]);
        s_B[li][c] = xdbl[m * 128 + 32 + c];
        s_C[li][c] = xdbl[m * 128 + 48 + c];
        s_g[li][c] = bf2f(g_bf[m * 1024 + d0 + c]);
    }
    const float aneg = -__expf(alog[(d0 + di) * 16 + s]);
    const float dp   = Dp[d0 + di];
    float h = hinit[(size_t)ch * NBDS + (b * 1024 + d0) * 16 + tid];
    __syncthreads();

#pragma unroll
    for (int j = 0; j < LCH; j++) {
        float dl = s_d[j][di];
        float uu = s_u[j][di];
        float a  = __expf(dl * aneg);
        float x  = dl * s_B[j][s] * uu;
        h = fmaf(a, h, x);
        float yp = h * s_C[j][s];
        yp += __shfl_xor(yp, 1, 16);
        yp += __shfl_xor(yp, 2, 16);
        yp += __shfl_xor(yp, 4, 16);
        yp += __shfl_xor(yp, 8, 16);
        if (s == 0) {
            float y = fmaf(uu, dp, yp) * s_g[j][di];
            y_bf[(size_t)(base_m + j) * 1024 + d0 + di] = f2bf(y);
        }
    }
}

// ---------------------------------------------------------------- launcher
extern "C" void kernel_launch(void* const* d_in, const int* in_sizes, int n_in,
                              void* d_out, int out_size, void* d_ws, size_t ws_size,
                              hipStream_t stream)
{
    const float* x         = (const float*)d_in[0];
    const float* conv_w    = (const float*)d_in[1];
    const float* conv_b    = (const float*)d_in[2];
    const float* pe_g      = (const float*)d_in[3];
    const float* pe_b      = (const float*)d_in[4];
    const float* ln_g      = (const float*)d_in[5];
    const float* ln_b      = (const float*)d_in[6];
    const float* in_proj_w = (const float*)d_in[7];
    const float* c1d_w     = (const float*)d_in[8];
    const float* c1d_b     = (const float*)d_in[9];
    const float* x_proj_w  = (const float*)d_in[10];
    const float* dt_proj_w = (const float*)d_in[11];
    const float* dt_proj_b = (const float*)d_in[12];
    const float* A_log     = (const float*)d_in[13];
    const float* Dp        = (const float*)d_in[14];
    const float* out_proj_w= (const float*)d_in[15];

    char* ws = (char*)d_ws;
    // ws layout, 61.6 MB total (aliases annotated):
    float* xz_x    = (float*)(ws + 0);             // 16 MB; aliases delta
    float* delta   = (float*)(ws + 0);             //   (xz_x dead after conv1d)
    u16*   A_patch = (u16*)  (ws + 0);             //   phase-1 alias (6 MB)
    float* xe      = (float*)(ws + 6291456);       //   phase-1 alias (8 MB)
    u16*   g_bf    = (u16*)  (ws + 16777216);      //  8 MB  silu(z) bf16
    float* tokens  = (float*)(ws + 25165824);      //  8 MB
    u16*   t_bf    = (u16*)  (ws + 33554432);      //  4 MB; aliases hinit
    float* hinit   = (float*)(ws + 33554432);      //   (t_bf dead after in_proj)
    u16*   u_bf    = (u16*)  (ws + 37748736);      //  8 MB
    float* xdbl    = (float*)(ws + 46137344);      //  2 MB
    float2* summ   = (float2*)(ws + 48234496);     //  8 MB; aliases y_bf
    u16*   y_bf    = (u16*)  (ws + 48234496);      //   (summ dead after carry)
    u16*   wPatch  = (u16*)  (ws + 56623104);      //  768 KB
    u16*   wIn     = (u16*)  (ws + 57409536);      //  4 MB
    u16*   wXp     = (u16*)  (ws + 61603840);      //  512 KB
    u16*   wOut    = (u16*)  (ws + 62128128);      //  2 MB
    u16*   wDt     = (u16*)  (ws + 64225280);      //  128 KB
    u16*   dt_bf   = (u16*)  (ws + 64356352);      //  256 KB

    dim3 blk(256);

    convert_weights<<<15104, blk, 0, stream>>>(conv_w, in_proj_w, x_proj_w,
                                               out_proj_w, dt_proj_w,
                                               wPatch, wIn, wXp, wOut, wDt);
    build_patches<<<12288, blk, 0, stream>>>(x, A_patch);
    gemm_bt<1><<<dim3(4, 32), blk, 0, stream>>>(A_patch, wPatch, xe, conv_b,
                                                nullptr, MTOK, DM_, KPATCH);
    ln_kernel<false><<<1024, blk, 0, stream>>>(xe, tokens, pe_g, pe_b);

    for (int i = 0; i < 2; i++) {
        ln_kernel<true><<<1024, blk, 0, stream>>>(tokens, t_bf,
                                                  ln_g + i * DM_, ln_b + i * DM_);
        // in_proj x-half: [4096 x 512] x [1024 x 512]^T -> xz_x f32
        gemm_bt<0><<<dim3(8, 32), blk, 0, stream>>>(t_bf, wIn + i * 1048576, xz_x,
                                                    nullptr, nullptr, MTOK, DIN, DM_);
        // in_proj z-half w/ silu epilogue -> g_bf bf16
        gemm_bt<4><<<dim3(8, 32), blk, 0, stream>>>(t_bf, wIn + i * 1048576 + 524288,
                                                    (float*)g_bf, nullptr, nullptr,
                                                    MTOK, DIN, DM_);
        conv1d_silu<<<16384, blk, 0, stream>>>(xz_x, c1d_w + i * 4096,
                                               c1d_b + i * 1024, u_bf);
        // x_proj: [4096 x 1024] x [128 x 1024]^T -> xdbl (dt|B|C|pad)
        gemm_bt<0><<<dim3(1, 32), blk, 0, stream>>>(u_bf, wXp + i * 131072, xdbl,
                                                    nullptr, nullptr, MTOK, 128, DIN);
        extract_dt<<<512, blk, 0, stream>>>(xdbl, dt_bf);
        // delta = softplus(dt @ dpw^T + dpb): [4096 x 32] x [1024 x 32]^T
        gemm_bt<3><<<dim3(8, 32), blk, 0, stream>>>(dt_bf, wDt + i * 32768, delta,
                                                    dt_proj_b + i * 1024, nullptr,
                                                    MTOK, DIN, DTR);
        scan_part1<<<dim3(64, 4, 16), blk, 0, stream>>>(delta, u_bf, xdbl,
                                                        A_log + i * 16384, summ);
        scan_carry<<<256, blk, 0, stream>>>(summ, hinit);
        scan_part2<<<dim3(64, 4, 16), blk, 0, stream>>>(delta, u_bf, xdbl, g_bf,
                                                        A_log + i * 16384,
                                                        Dp + i * 1024, hinit, y_bf);
        // out_proj + residual: [4096 x 1024] x [512 x 1024]^T + tokens
        float* dst = (i == 1) ? (float*)d_out : tokens;
        gemm_bt<2><<<dim3(4, 32), blk, 0, stream>>>(y_bf, wOut + i * 524288, dst,
                                                    nullptr, tokens, MTOK, DM_, DIN);
    }
}

// Round 3
// 513.247 us; speedup vs baseline: 2.1919x; 1.1667x over previous
//
#include <hip/hip_runtime.h>

// ResidualMambaTokenStage: patch-embed conv (as GEMM) + ch-LN, then 2x
// (LN -> in_proj -> causal dwconv1d+silu -> x_proj -> dt/softplus ->
//  selective scan -> gate -> out_proj + residual).
// R3: scan restructured -- one thread owns all 16 states of a (b,d,chunk):
// no cross-lane reduction, 16-way ILP, one barrier per kernel. delta in bf16.

#define BB   4
#define LL   1024
#define MTOK 4096
#define DM_  512
#define DIN  1024
#define DST  16
#define DTR  32
#define KPATCH 768
#define LCH  32          // chunk length
#define NCH  32          // chunks per sequence
#define NBDS 65536       // B * DIN * DST carry sequences

typedef unsigned short u16;
typedef __attribute__((ext_vector_type(8))) short bf16x8_t;
typedef __attribute__((ext_vector_type(4))) float floatx4_t;

__device__ inline u16 f2bf(float f) {
    unsigned int u = __float_as_uint(f);
    unsigned int r = (u + 0x7FFFu + ((u >> 16) & 1u)) >> 16;   // RNE
    return (u16)r;
}
__device__ inline float bf2f(u16 h) {
    return __uint_as_float(((unsigned int)h) << 16);
}

// ---------------------------------------------------------------- weights
__global__ __launch_bounds__(256) void convert_weights(
    const float* __restrict__ conv_w, const float* __restrict__ in_proj_w,
    const float* __restrict__ x_proj_w, const float* __restrict__ out_proj_w,
    const float* __restrict__ dt_proj_w,
    u16* __restrict__ wPatch, u16* __restrict__ wIn,
    u16* __restrict__ wXp, u16* __restrict__ wOut, u16* __restrict__ wDt)
{
    int g = blockIdx.x * 256 + threadIdx.x;
    const int N0 = 393216;            // conv_w 512*768
    const int N1 = N0 + 2097152;      // in_proj 2*2048*512
    const int N2 = N1 + 262144;       // x_proj padded 2*128*1024
    const int N3 = N2 + 1048576;      // out_proj 2*512*1024
    const int N4 = N3 + 65536;        // dt_proj_w 2*1024*32
    if (g < N0) {
        wPatch[g] = f2bf(conv_w[g]);
    } else if (g < N1) {
        int o = g - N0; wIn[o] = f2bf(in_proj_w[o]);
    } else if (g < N2) {
        int o = g - N1;
        int blk = o >> 17, rem = o & 131071;
        int n = rem >> 10, k = rem & 1023;
        wXp[o] = (n < 64) ? f2bf(x_proj_w[blk * 65536 + n * 1024 + k]) : (u16)0;
    } else if (g < N3) {
        int o = g - N2; wOut[o] = f2bf(out_proj_w[o]);
    } else if (g < N4) {
        int o = g - N3; wDt[o] = f2bf(dt_proj_w[o]);
    }
}

// ------------------------------------------------------------- patch im2col
__global__ __launch_bounds__(256) void build_patches(
    const float* __restrict__ x, u16* __restrict__ Ap)
{
    int g = blockIdx.x * 256 + threadIdx.x;
    int m = g / KPATCH, k = g % KPATCH;
    int b = m >> 10, l = m & 1023, hp = l >> 5, wp = l & 31;
    int c = k >> 8, rem = k & 255, py = rem >> 4, px = rem & 15;
    float v = x[(((size_t)(b * 3 + c)) * 512 + hp * 16 + py) * 512 + wp * 16 + px];
    Ap[g] = f2bf(v);
}

// ------------------------------------------------------------------- GEMM
// C[M][N] = A[M][K] * Bt[N][K]^T. EPI: 0 none, 1 +bias, 2 +res,
// 3 softplus(v+bias) bf16 out, 4 silu(v) bf16 out.
template<int EPI>
__global__ __launch_bounds__(256, 2) void gemm_bt(
    const u16* __restrict__ A, const u16* __restrict__ Bt,
    float* __restrict__ C, const float* __restrict__ bias,
    const float* __restrict__ res, int M, int N, int K)
{
    __shared__ short As[128 * 40];
    __shared__ short Bs[128 * 40];
    const int tid  = threadIdx.x;
    const int lane = tid & 63;
    const int wid  = tid >> 6;
    const int quad = lane >> 4;
    const int l16  = lane & 15;
    const int wm = wid >> 1, wn = wid & 1;
    const int m0 = blockIdx.y * 128, n0 = blockIdx.x * 128;

    floatx4_t acc[4][4] = {};

    const int c0 = tid, c1 = tid + 256;
    const int r0 = c0 >> 2, o0 = (c0 & 3) * 8;
    const int r1 = c1 >> 2, o1 = (c1 & 3) * 8;

    for (int kk = 0; kk < K; kk += 32) {
        *(bf16x8_t*)&As[r0 * 40 + o0] = *(const bf16x8_t*)&A[(size_t)(m0 + r0) * K + kk + o0];
        *(bf16x8_t*)&As[r1 * 40 + o1] = *(const bf16x8_t*)&A[(size_t)(m0 + r1) * K + kk + o1];
        *(bf16x8_t*)&Bs[r0 * 40 + o0] = *(const bf16x8_t*)&Bt[(size_t)(n0 + r0) * K + kk + o0];
        *(bf16x8_t*)&Bs[r1 * 40 + o1] = *(const bf16x8_t*)&Bt[(size_t)(n0 + r1) * K + kk + o1];
        __syncthreads();
        bf16x8_t af[4], bfr[4];
#pragma unroll
        for (int t = 0; t < 4; t++)
            af[t] = *(const bf16x8_t*)&As[(wm * 64 + t * 16 + l16) * 40 + quad * 8];
#pragma unroll
        for (int t = 0; t < 4; t++)
            bfr[t] = *(const bf16x8_t*)&Bs[(wn * 64 + t * 16 + l16) * 40 + quad * 8];
#pragma unroll
        for (int tm = 0; tm < 4; tm++)
#pragma unroll
            for (int tn = 0; tn < 4; tn++)
                acc[tm][tn] = __builtin_amdgcn_mfma_f32_16x16x32_bf16(
                    af[tm], bfr[tn], acc[tm][tn], 0, 0, 0);
        __syncthreads();
    }
#pragma unroll
    for (int tm = 0; tm < 4; tm++) {
#pragma unroll
        for (int r = 0; r < 4; r++) {
            int gr = m0 + wm * 64 + tm * 16 + quad * 4 + r;
#pragma unroll
            for (int tn = 0; tn < 4; tn++) {
                int gc = n0 + wn * 64 + tn * 16 + l16;
                float v = acc[tm][tn][r];
                if (EPI == 1) v += bias[gc];
                if (EPI == 2) v += res[(size_t)gr * N + gc];
                if (EPI == 3) {
                    v += bias[gc];
                    v = (v > 20.f) ? v : log1pf(__expf(v));
                    ((u16*)C)[(size_t)gr * N + gc] = f2bf(v);
                } else if (EPI == 4) {
                    float sv = v / (1.f + __expf(-v));
                    ((u16*)C)[(size_t)gr * N + gc] = f2bf(sv);
                } else {
                    C[(size_t)gr * N + gc] = v;
                }
            }
        }
    }
}

// --------------------------------------------------------------------- LN
template<bool BF16OUT>
__global__ __launch_bounds__(256) void ln_kernel(
    const float* __restrict__ in, void* __restrict__ out,
    const float* __restrict__ g, const float* __restrict__ b)
{
    int token = blockIdx.x * 4 + (threadIdx.x >> 6);
    int lane  = threadIdx.x & 63;
    const float* row = in + (size_t)token * DM_;
    float v[8], s = 0.f, q = 0.f;
#pragma unroll
    for (int j = 0; j < 8; j++) {
        v[j] = row[lane + j * 64];
        s += v[j]; q = fmaf(v[j], v[j], q);
    }
#pragma unroll
    for (int off = 32; off >= 1; off >>= 1) {
        s += __shfl_xor(s, off);
        q += __shfl_xor(q, off);
    }
    float mean = s * (1.f / DM_);
    float var  = q * (1.f / DM_) - mean * mean;
    float inv  = rsqrtf(var + 1e-5f);
#pragma unroll
    for (int j = 0; j < 8; j++) {
        int idx = lane + j * 64;
        float o = (v[j] - mean) * inv * g[idx] + b[idx];
        if (BF16OUT) ((u16*)out)[(size_t)token * DM_ + idx] = f2bf(o);
        else         ((float*)out)[(size_t)token * DM_ + idx] = o;
    }
}

// ----------------------------------------------------- causal dwconv1d+silu
__global__ __launch_bounds__(256) void conv1d_silu(
    const float* __restrict__ xz_x, const float* __restrict__ w,
    const float* __restrict__ cb, u16* __restrict__ u_bf)
{
    int g = blockIdx.x * 256 + threadIdx.x;      // 4096*1024
    int d = g & 1023, m = g >> 10, l = m & 1023;
    float acc = cb[d];
#pragma unroll
    for (int j = 0; j < 4; j++) {
        int lj = l + j - 3;
        if (lj >= 0)
            acc = fmaf(xz_x[(size_t)(m + j - 3) * 1024 + d], w[d * 4 + j], acc);
    }
    float uu = acc / (1.f + __expf(-acc));
    u_bf[g] = f2bf(uu);
}

// ------------------------------------------------------------ dt extraction
__global__ __launch_bounds__(256) void extract_dt(
    const float* __restrict__ xdbl, u16* __restrict__ dt_bf)
{
    int g = blockIdx.x * 256 + threadIdx.x;      // 4096*32
    int m = g >> 5, c = g & 31;
    dt_bf[g] = f2bf(xdbl[(size_t)m * 128 + c]);
}

// ------------------------------------------------- chunk-parallel scan: P1
// Thread owns (b, d, chunk), all 16 states in registers.
// Summary: h_end_s = P_s * h_start_s + Q_s;  P_s = exp(aneg_s * sum(delta)).
__global__ __launch_bounds__(256) void scan_part1(
    const u16* __restrict__ delta_bf, const u16* __restrict__ u_bf,
    const float* __restrict__ xdbl, const float* __restrict__ alog,
    float* __restrict__ summP, float* __restrict__ summQ)
{
    __shared__ float sB[LCH][16];
    const int tid = threadIdx.x;
    const int d  = blockIdx.x * 256 + tid;
    const int b  = blockIdx.y, ch = blockIdx.z;
    const int m0 = b * LL + ch * LCH;

    for (int e = tid; e < LCH * 16; e += 256) {
        int li = e >> 4, s = e & 15;
        sB[li][s] = xdbl[(size_t)(m0 + li) * 128 + 32 + s];
    }
    float aneg[16];
#pragma unroll
    for (int s = 0; s < 16; s++) aneg[s] = -__expf(alog[d * 16 + s]);
    __syncthreads();

    float Q[16] = {};
    float dsum = 0.f;
#pragma unroll 4
    for (int j = 0; j < LCH; j++) {
        float dl = bf2f(delta_bf[(size_t)(m0 + j) * 1024 + d]);
        float du = dl * bf2f(u_bf[(size_t)(m0 + j) * 1024 + d]);
        dsum += dl;
#pragma unroll
        for (int s = 0; s < 16; s++) {
            float a = __expf(dl * aneg[s]);
            Q[s] = fmaf(a, Q[s], sB[j][s] * du);
        }
    }
    size_t base = (size_t)ch * NBDS + ((size_t)b * 1024 + d) * 16;
#pragma unroll
    for (int s = 0; s < 16; s++) {
        summP[base + s] = __expf(dsum * aneg[s]);
        summQ[base + s] = Q[s];
    }
}

// ------------------------------------------------- carry scan over chunks
__global__ __launch_bounds__(256) void scan_carry(
    const float* __restrict__ summP, const float* __restrict__ summQ,
    float* __restrict__ hinit)
{
    int bds = blockIdx.x * 256 + threadIdx.x;    // 65536
    float h = 0.f;
#pragma unroll
    for (int c = 0; c < NCH; c++) {
        hinit[(size_t)c * NBDS + bds] = h;
        h = fmaf(summP[(size_t)c * NBDS + bds], h, summQ[(size_t)c * NBDS + bds]);
    }
}

// ------------------------------------------------- chunk-parallel scan: P2
// Replay chunk with correct h0; y_l = sum_s h_s*C_s (in-register); gate.
__global__ __launch_bounds__(256) void scan_part2(
    const u16* __restrict__ delta_bf, const u16* __restrict__ u_bf,
    const float* __restrict__ xdbl, const u16* __restrict__ g_bf,
    const float* __restrict__ alog, const float* __restrict__ Dp,
    const float* __restrict__ hinit, u16* __restrict__ y_bf)
{
    __shared__ float sB[LCH][16];
    __shared__ float sC[LCH][16];
    const int tid = threadIdx.x;
    const int d  = blockIdx.x * 256 + tid;
    const int b  = blockIdx.y, ch = blockIdx.z;
    const int m0 = b * LL + ch * LCH;

    for (int e = tid; e < LCH * 16; e += 256) {
        int li = e >> 4, s = e & 15;
        sB[li][s] = xdbl[(size_t)(m0 + li) * 128 + 32 + s];
        sC[li][s] = xdbl[(size_t)(m0 + li) * 128 + 48 + s];
    }
    float aneg[16];
#pragma unroll
    for (int s = 0; s < 16; s++) aneg[s] = -__expf(alog[d * 16 + s]);
    const float dp = Dp[d];
    float h[16];
    size_t hbase = (size_t)ch * NBDS + ((size_t)b * 1024 + d) * 16;
#pragma unroll
    for (int s = 0; s < 16; s++) h[s] = hinit[hbase + s];
    __syncthreads();

#pragma unroll 4
    for (int j = 0; j < LCH; j++) {
        size_t m = (size_t)(m0 + j) * 1024 + d;
        float dl = bf2f(delta_bf[m]);
        float uu = bf2f(u_bf[m]);
        float gg = bf2f(g_bf[m]);
        float du = dl * uu;
        float y = 0.f;
#pragma unroll
        for (int s = 0; s < 16; s++) {
            float a = __expf(dl * aneg[s]);
            h[s] = fmaf(a, h[s], sB[j][s] * du);
            y = fmaf(h[s], sC[j][s], y);
        }
        y_bf[m] = f2bf(fmaf(uu, dp, y) * gg);
    }
}

// ---------------------------------------------------------------- launcher
extern "C" void kernel_launch(void* const* d_in, const int* in_sizes, int n_in,
                              void* d_out, int out_size, void* d_ws, size_t ws_size,
                              hipStream_t stream)
{
    const float* x         = (const float*)d_in[0];
    const float* conv_w    = (const float*)d_in[1];
    const float* conv_b    = (const float*)d_in[2];
    const float* pe_g      = (const float*)d_in[3];
    const float* pe_b      = (const float*)d_in[4];
    const float* ln_g      = (const float*)d_in[5];
    const float* ln_b      = (const float*)d_in[6];
    const float* in_proj_w = (const float*)d_in[7];
    const float* c1d_w     = (const float*)d_in[8];
    const float* c1d_b     = (const float*)d_in[9];
    const float* x_proj_w  = (const float*)d_in[10];
    const float* dt_proj_w = (const float*)d_in[11];
    const float* dt_proj_b = (const float*)d_in[12];
    const float* A_log     = (const float*)d_in[13];
    const float* Dp        = (const float*)d_in[14];
    const float* out_proj_w= (const float*)d_in[15];

    char* ws = (char*)d_ws;
    // ws layout, 64.9 MB total. R1 slab @0 (16MB) is time-multiplexed:
    //   phase1: A_patch(6MB)+xe(8MB); per-iter: xz_x(16MB) -> summP(8)+summQ(8)
    //   -> y_bf(8). hinit(8MB) overlays t_bf(4MB).
    float* xz_x    = (float*)(ws + 0);
    u16*   A_patch = (u16*)  (ws + 0);
    float* xe      = (float*)(ws + 6291456);
    float* summP   = (float*)(ws + 0);
    float* summQ   = (float*)(ws + 8388608);
    u16*   y_bf    = (u16*)  (ws + 0);
    u16*   g_bf    = (u16*)  (ws + 16777216);      //  8 MB (phase1: wPatch)
    u16*   wPatch  = (u16*)  (ws + 16777216);
    float* tokens  = (float*)(ws + 25165824);      //  8 MB
    u16*   t_bf    = (u16*)  (ws + 33554432);      //  4 MB
    float* hinit   = (float*)(ws + 33554432);      //  8 MB (over t_bf)
    u16*   u_bf    = (u16*)  (ws + 41943040);      //  8 MB
    u16*   delta_bf= (u16*)  (ws + 50331648);      //  8 MB
    float* xdbl    = (float*)(ws + 58720256);      //  2 MB
    u16*   wIn     = (u16*)  (ws + 60817408);      //  4 MB
    u16*   wXp     = (u16*)  (ws + 65011712);      //  512 KB
    u16*   wOut    = (u16*)  (ws + 65536000);      //  2 MB
    u16*   wDt     = (u16*)  (ws + 67633152);      //  128 KB
    u16*   dt_bf   = (u16*)  (ws + 67764224);      //  256 KB -> end 68,026,368

    dim3 blk(256);

    convert_weights<<<15104, blk, 0, stream>>>(conv_w, in_proj_w, x_proj_w,
                                               out_proj_w, dt_proj_w,
                                               wPatch, wIn, wXp, wOut, wDt);
    build_patches<<<12288, blk, 0, stream>>>(x, A_patch);
    gemm_bt<1><<<dim3(4, 32), blk, 0, stream>>>(A_patch, wPatch, xe, conv_b,
                                                nullptr, MTOK, DM_, KPATCH);
    ln_kernel<false><<<1024, blk, 0, stream>>>(xe, tokens, pe_g, pe_b);

    for (int i = 0; i < 2; i++) {
        ln_kernel<true><<<1024, blk, 0, stream>>>(tokens, t_bf,
                                                  ln_g + i * DM_, ln_b + i * DM_);
        // in_proj x-half: [4096 x 512] x [1024 x 512]^T -> xz_x f32
        gemm_bt<0><<<dim3(8, 32), blk, 0, stream>>>(t_bf, wIn + i * 1048576, xz_x,
                                                    nullptr, nullptr, MTOK, DIN, DM_);
        // in_proj z-half w/ silu epilogue -> g_bf bf16
        gemm_bt<4><<<dim3(8, 32), blk, 0, stream>>>(t_bf, wIn + i * 1048576 + 524288,
                                                    (float*)g_bf, nullptr, nullptr,
                                                    MTOK, DIN, DM_);
        conv1d_silu<<<16384, blk, 0, stream>>>(xz_x, c1d_w + i * 4096,
                                               c1d_b + i * 1024, u_bf);
        // x_proj: [4096 x 1024] x [128 x 1024]^T -> xdbl (dt|B|C|pad)
        gemm_bt<0><<<dim3(1, 32), blk, 0, stream>>>(u_bf, wXp + i * 131072, xdbl,
                                                    nullptr, nullptr, MTOK, 128, DIN);
        extract_dt<<<512, blk, 0, stream>>>(xdbl, dt_bf);
        // delta = softplus(dt @ dpw^T + dpb) -> bf16
        gemm_bt<3><<<dim3(8, 32), blk, 0, stream>>>(dt_bf, wDt + i * 32768,
                                                    (float*)delta_bf,
                                                    dt_proj_b + i * 1024, nullptr,
                                                    MTOK, DIN, DTR);
        scan_part1<<<dim3(4, 4, NCH), blk, 0, stream>>>(delta_bf, u_bf, xdbl,
                                                        A_log + i * 16384,
                                                        summP, summQ);
        scan_carry<<<256, blk, 0, stream>>>(summP, summQ, hinit);
        scan_part2<<<dim3(4, 4, NCH), blk, 0, stream>>>(delta_bf, u_bf, xdbl, g_bf,
                                                        A_log + i * 16384,
                                                        Dp + i * 1024, hinit, y_bf);
        // out_proj + residual: [4096 x 1024] x [512 x 1024]^T + tokens
        float* dst = (i == 1) ? (float*)d_out : tokens;
        gemm_bt<2><<<dim3(4, 32), blk, 0, stream>>>(y_bf, wOut + i * 524288, dst,
                                                    nullptr, tokens, MTOK, DM_, DIN);
    }
}

// Round 4
// 489.272 us; speedup vs baseline: 2.2993x; 1.0490x over previous
//
#include <hip/hip_runtime.h>

// ResidualMambaTokenStage: patch-embed conv (as GEMM) + ch-LN, then 2x
// (LN -> in_proj -> causal dwconv1d+silu -> x_proj -> dt/softplus ->
//  selective scan -> gate -> out_proj + residual).
// R4: m97-style GEMM staging (global_load_lds width=16, unpadded 128x32 LDS
// tiles); in_proj halves merged into one N=2048 GEMM w/ dual bf16 epilogue;
// xz kept in bf16 (conv1d reads half the bytes).

#define BB   4
#define LL   1024
#define MTOK 4096
#define DM_  512
#define DIN  1024
#define DST  16
#define DTR  32
#define KPATCH 768
#define LCH  32          // scan chunk length
#define NCH  32          // chunks per sequence
#define NBDS 65536       // B * DIN * DST carry sequences

typedef unsigned short u16;
typedef __attribute__((ext_vector_type(8))) short bf16x8_t;
typedef __attribute__((ext_vector_type(4))) float floatx4_t;

__device__ inline u16 f2bf(float f) {
    unsigned int u = __float_as_uint(f);
    unsigned int r = (u + 0x7FFFu + ((u >> 16) & 1u)) >> 16;   // RNE
    return (u16)r;
}
__device__ inline float bf2f(u16 h) {
    return __uint_as_float(((unsigned int)h) << 16);
}

// ---------------------------------------------------------------- weights
__global__ __launch_bounds__(256) void convert_weights(
    const float* __restrict__ conv_w, const float* __restrict__ in_proj_w,
    const float* __restrict__ x_proj_w, const float* __restrict__ out_proj_w,
    const float* __restrict__ dt_proj_w,
    u16* __restrict__ wPatch, u16* __restrict__ wIn,
    u16* __restrict__ wXp, u16* __restrict__ wOut, u16* __restrict__ wDt)
{
    int g = blockIdx.x * 256 + threadIdx.x;
    const int N0 = 393216;            // conv_w 512*768
    const int N1 = N0 + 2097152;      // in_proj 2*2048*512
    const int N2 = N1 + 262144;       // x_proj padded 2*128*1024
    const int N3 = N2 + 1048576;      // out_proj 2*512*1024
    const int N4 = N3 + 65536;        // dt_proj_w 2*1024*32
    if (g < N0) {
        wPatch[g] = f2bf(conv_w[g]);
    } else if (g < N1) {
        int o = g - N0; wIn[o] = f2bf(in_proj_w[o]);
    } else if (g < N2) {
        int o = g - N1;
        int blk = o >> 17, rem = o & 131071;
        int n = rem >> 10, k = rem & 1023;
        wXp[o] = (n < 64) ? f2bf(x_proj_w[blk * 65536 + n * 1024 + k]) : (u16)0;
    } else if (g < N3) {
        int o = g - N2; wOut[o] = f2bf(out_proj_w[o]);
    } else if (g < N4) {
        int o = g - N3; wDt[o] = f2bf(dt_proj_w[o]);
    }
}

// ------------------------------------------------------------- patch im2col
__global__ __launch_bounds__(256) void build_patches(
    const float* __restrict__ x, u16* __restrict__ Ap)
{
    int g = blockIdx.x * 256 + threadIdx.x;
    int m = g / KPATCH, k = g % KPATCH;
    int b = m >> 10, l = m & 1023, hp = l >> 5, wp = l & 31;
    int c = k >> 8, rem = k & 255, py = rem >> 4, px = rem & 15;
    float v = x[(((size_t)(b * 3 + c)) * 512 + hp * 16 + py) * 512 + wp * 16 + px];
    Ap[g] = f2bf(v);
}

// ------------------------------------------------------------------- GEMM
// C[M][N] = A[M][K] * Bt[N][K]^T, bf16 in. m97 staging: unpadded [128][32]
// LDS tiles filled by global_load_lds dwordx4 (wave-uniform base + lane*16).
// EPI: 0 f32, 1 f32+bias, 2 f32+res, 3 softplus(v+bias)->bf16,
//      5 dual: col<1024 -> bf16 C, col>=1024 -> silu -> bf16 aux.
template<int EPI>
__global__ __launch_bounds__(256, 2) void gemm_bt(
    const u16* __restrict__ A, const u16* __restrict__ Bt,
    float* __restrict__ C, const float* __restrict__ bias,
    const float* __restrict__ res, u16* __restrict__ aux,
    int M, int N, int K)
{
    __shared__ short As[128 * 32];    // 8 KB, unpadded (global_load_lds layout)
    __shared__ short Bs[128 * 32];
    const int tid  = threadIdx.x;
    const int lane = tid & 63;
    const int wv   = tid >> 6;
    const int quad = lane >> 4;
    const int l16  = lane & 15;
    const int wm = wv >> 1, wn = wv & 1;
    const int m0 = blockIdx.y * 128, n0 = blockIdx.x * 128;

    floatx4_t acc[4][4] = {};

    // staging: wave wv, issue i covers rows i*64 + wv*16 + lane/4,
    // col shorts (lane&3)*8; LDS dest = base + lane*16B (HW).
    const int srow0 = wv * 16 + (lane >> 2);
    const int scol  = (lane & 3) * 8;

    for (int kk = 0; kk < K; kk += 32) {
        __builtin_amdgcn_global_load_lds(
            (const __attribute__((address_space(1))) unsigned int*)
                (A + (size_t)(m0 + srow0) * K + kk + scol),
            (__attribute__((address_space(3))) unsigned int*)(As + wv * 16 * 32),
            16, 0, 0);
        __builtin_amdgcn_global_load_lds(
            (const __attribute__((address_space(1))) unsigned int*)
                (A + (size_t)(m0 + 64 + srow0) * K + kk + scol),
            (__attribute__((address_space(3))) unsigned int*)(As + (64 + wv * 16) * 32),
            16, 0, 0);
        __builtin_amdgcn_global_load_lds(
            (const __attribute__((address_space(1))) unsigned int*)
                (Bt + (size_t)(n0 + srow0) * K + kk + scol),
            (__attribute__((address_space(3))) unsigned int*)(Bs + wv * 16 * 32),
            16, 0, 0);
        __builtin_amdgcn_global_load_lds(
            (const __attribute__((address_space(1))) unsigned int*)
                (Bt + (size_t)(n0 + 64 + srow0) * K + kk + scol),
            (__attribute__((address_space(3))) unsigned int*)(Bs + (64 + wv * 16) * 32),
            16, 0, 0);
        __syncthreads();
        bf16x8_t af[4], bfr[4];
#pragma unroll
        for (int t = 0; t < 4; t++)
            af[t] = *(const bf16x8_t*)&As[(wm * 64 + t * 16 + l16) * 32 + quad * 8];
#pragma unroll
        for (int t = 0; t < 4; t++)
            bfr[t] = *(const bf16x8_t*)&Bs[(wn * 64 + t * 16 + l16) * 32 + quad * 8];
#pragma unroll
        for (int tm = 0; tm < 4; tm++)
#pragma unroll
            for (int tn = 0; tn < 4; tn++)
                acc[tm][tn] = __builtin_amdgcn_mfma_f32_16x16x32_bf16(
                    af[tm], bfr[tn], acc[tm][tn], 0, 0, 0);
        __syncthreads();
    }
#pragma unroll
    for (int tm = 0; tm < 4; tm++) {
#pragma unroll
        for (int r = 0; r < 4; r++) {
            int gr = m0 + wm * 64 + tm * 16 + quad * 4 + r;
#pragma unroll
            for (int tn = 0; tn < 4; tn++) {
                int gc = n0 + wn * 64 + tn * 16 + l16;
                float v = acc[tm][tn][r];
                if (EPI == 1) v += bias[gc];
                if (EPI == 2) v += res[(size_t)gr * N + gc];
                if (EPI == 3) {
                    v += bias[gc];
                    v = (v > 20.f) ? v : log1pf(__expf(v));
                    ((u16*)C)[(size_t)gr * N + gc] = f2bf(v);
                } else if (EPI == 5) {
                    if (gc < 1024) {
                        ((u16*)C)[(size_t)gr * 1024 + gc] = f2bf(v);
                    } else {
                        float sv = v / (1.f + __expf(-v));
                        aux[(size_t)gr * 1024 + gc - 1024] = f2bf(sv);
                    }
                } else {
                    C[(size_t)gr * N + gc] = v;
                }
            }
        }
    }
}

// --------------------------------------------------------------------- LN
template<bool BF16OUT>
__global__ __launch_bounds__(256) void ln_kernel(
    const float* __restrict__ in, void* __restrict__ out,
    const float* __restrict__ g, const float* __restrict__ b)
{
    int token = blockIdx.x * 4 + (threadIdx.x >> 6);
    int lane  = threadIdx.x & 63;
    const float* row = in + (size_t)token * DM_;
    float v[8], s = 0.f, q = 0.f;
#pragma unroll
    for (int j = 0; j < 8; j++) {
        v[j] = row[lane + j * 64];
        s += v[j]; q = fmaf(v[j], v[j], q);
    }
#pragma unroll
    for (int off = 32; off >= 1; off >>= 1) {
        s += __shfl_xor(s, off);
        q += __shfl_xor(q, off);
    }
    float mean = s * (1.f / DM_);
    float var  = q * (1.f / DM_) - mean * mean;
    float inv  = rsqrtf(var + 1e-5f);
#pragma unroll
    for (int j = 0; j < 8; j++) {
        int idx = lane + j * 64;
        float o = (v[j] - mean) * inv * g[idx] + b[idx];
        if (BF16OUT) ((u16*)out)[(size_t)token * DM_ + idx] = f2bf(o);
        else         ((float*)out)[(size_t)token * DM_ + idx] = o;
    }
}

// ----------------------------------------------------- causal dwconv1d+silu
// xz_bf is [4096][1024] bf16 (the x-half of in_proj output).
__global__ __launch_bounds__(256) void conv1d_silu(
    const u16* __restrict__ xz_bf, const float* __restrict__ w,
    const float* __restrict__ cb, u16* __restrict__ u_bf)
{
    int g = blockIdx.x * 256 + threadIdx.x;      // 4096*1024
    int d = g & 1023, m = g >> 10, l = m & 1023;
    float acc = cb[d];
#pragma unroll
    for (int j = 0; j < 4; j++) {
        int lj = l + j - 3;
        if (lj >= 0)
            acc = fmaf(bf2f(xz_bf[(size_t)(m + j - 3) * 1024 + d]), w[d * 4 + j], acc);
    }
    float uu = acc / (1.f + __expf(-acc));
    u_bf[g] = f2bf(uu);
}

// ------------------------------------------------------------ dt extraction
__global__ __launch_bounds__(256) void extract_dt(
    const float* __restrict__ xdbl, u16* __restrict__ dt_bf)
{
    int g = blockIdx.x * 256 + threadIdx.x;      // 4096*32
    int m = g >> 5, c = g & 31;
    dt_bf[g] = f2bf(xdbl[(size_t)m * 128 + c]);
}

// ------------------------------------------------- chunk-parallel scan: P1
// Thread owns (b, d, chunk), all 16 states in registers.
__global__ __launch_bounds__(256) void scan_part1(
    const u16* __restrict__ delta_bf, const u16* __restrict__ u_bf,
    const float* __restrict__ xdbl, const float* __restrict__ alog,
    float* __restrict__ summP, float* __restrict__ summQ)
{
    __shared__ float sB[LCH][16];
    const int tid = threadIdx.x;
    const int d  = blockIdx.x * 256 + tid;
    const int b  = blockIdx.y, ch = blockIdx.z;
    const int m0 = b * LL + ch * LCH;

    for (int e = tid; e < LCH * 16; e += 256) {
        int li = e >> 4, s = e & 15;
        sB[li][s] = xdbl[(size_t)(m0 + li) * 128 + 32 + s];
    }
    float aneg[16];
#pragma unroll
    for (int s = 0; s < 16; s++) aneg[s] = -__expf(alog[d * 16 + s]);
    __syncthreads();

    float Q[16] = {};
    float dsum = 0.f;
#pragma unroll 4
    for (int j = 0; j < LCH; j++) {
        float dl = bf2f(delta_bf[(size_t)(m0 + j) * 1024 + d]);
        float du = dl * bf2f(u_bf[(size_t)(m0 + j) * 1024 + d]);
        dsum += dl;
#pragma unroll
        for (int s = 0; s < 16; s++) {
            float a = __expf(dl * aneg[s]);
            Q[s] = fmaf(a, Q[s], sB[j][s] * du);
        }
    }
    size_t base = (size_t)ch * NBDS + ((size_t)b * 1024 + d) * 16;
#pragma unroll
    for (int s = 0; s < 16; s++) {
        summP[base + s] = __expf(dsum * aneg[s]);
        summQ[base + s] = Q[s];
    }
}

// ------------------------------------------------- carry scan over chunks
__global__ __launch_bounds__(256) void scan_carry(
    const float* __restrict__ summP, const float* __restrict__ summQ,
    float* __restrict__ hinit)
{
    int bds = blockIdx.x * 256 + threadIdx.x;    // 65536
    float h = 0.f;
#pragma unroll
    for (int c = 0; c < NCH; c++) {
        hinit[(size_t)c * NBDS + bds] = h;
        h = fmaf(summP[(size_t)c * NBDS + bds], h, summQ[(size_t)c * NBDS + bds]);
    }
}

// ------------------------------------------------- chunk-parallel scan: P2
__global__ __launch_bounds__(256) void scan_part2(
    const u16* __restrict__ delta_bf, const u16* __restrict__ u_bf,
    const float* __restrict__ xdbl, const u16* __restrict__ g_bf,
    const float* __restrict__ alog, const float* __restrict__ Dp,
    const float* __restrict__ hinit, u16* __restrict__ y_bf)
{
    __shared__ float sB[LCH][16];
    __shared__ float sC[LCH][16];
    const int tid = threadIdx.x;
    const int d  = blockIdx.x * 256 + tid;
    const int b  = blockIdx.y, ch = blockIdx.z;
    const int m0 = b * LL + ch * LCH;

    for (int e = tid; e < LCH * 16; e += 256) {
        int li = e >> 4, s = e & 15;
        sB[li][s] = xdbl[(size_t)(m0 + li) * 128 + 32 + s];
        sC[li][s] = xdbl[(size_t)(m0 + li) * 128 + 48 + s];
    }
    float aneg[16];
#pragma unroll
    for (int s = 0; s < 16; s++) aneg[s] = -__expf(alog[d * 16 + s]);
    const float dp = Dp[d];
    float h[16];
    size_t hbase = (size_t)ch * NBDS + ((size_t)b * 1024 + d) * 16;
#pragma unroll
    for (int s = 0; s < 16; s++) h[s] = hinit[hbase + s];
    __syncthreads();

#pragma unroll 4
    for (int j = 0; j < LCH; j++) {
        size_t m = (size_t)(m0 + j) * 1024 + d;
        float dl = bf2f(delta_bf[m]);
        float uu = bf2f(u_bf[m]);
        float gg = bf2f(g_bf[m]);
        float du = dl * uu;
        float y = 0.f;
#pragma unroll
        for (int s = 0; s < 16; s++) {
            float a = __expf(dl * aneg[s]);
            h[s] = fmaf(a, h[s], sB[j][s] * du);
            y = fmaf(h[s], sC[j][s], y);
        }
        y_bf[m] = f2bf(fmaf(uu, dp, y) * gg);
    }
}

// ---------------------------------------------------------------- launcher
extern "C" void kernel_launch(void* const* d_in, const int* in_sizes, int n_in,
                              void* d_out, int out_size, void* d_ws, size_t ws_size,
                              hipStream_t stream)
{
    const float* x         = (const float*)d_in[0];
    const float* conv_w    = (const float*)d_in[1];
    const float* conv_b    = (const float*)d_in[2];
    const float* pe_g      = (const float*)d_in[3];
    const float* pe_b      = (const float*)d_in[4];
    const float* ln_g      = (const float*)d_in[5];
    const float* ln_b      = (const float*)d_in[6];
    const float* in_proj_w = (const float*)d_in[7];
    const float* c1d_w     = (const float*)d_in[8];
    const float* c1d_b     = (const float*)d_in[9];
    const float* x_proj_w  = (const float*)d_in[10];
    const float* dt_proj_w = (const float*)d_in[11];
    const float* dt_proj_b = (const float*)d_in[12];
    const float* A_log     = (const float*)d_in[13];
    const float* Dp        = (const float*)d_in[14];
    const float* out_proj_w= (const float*)d_in[15];

    char* ws = (char*)d_ws;
    // ws layout. Slab @0 (16MB) time-multiplexed:
    //   phase1: A_patch(6MB)+xe(8MB); per-iter: xz_bf(8MB, dead after conv1d)
    //   -> summP(8)+summQ(8) -> y_bf(8, over summP after carry).
    u16*   A_patch = (u16*)  (ws + 0);
    float* xe      = (float*)(ws + 6291456);
    u16*   xz_bf   = (u16*)  (ws + 0);
    float* summP   = (float*)(ws + 0);
    float* summQ   = (float*)(ws + 8388608);
    u16*   y_bf    = (u16*)  (ws + 0);
    u16*   g_bf    = (u16*)  (ws + 16777216);      //  8 MB (phase1: wPatch)
    u16*   wPatch  = (u16*)  (ws + 16777216);
    float* tokens  = (float*)(ws + 25165824);      //  8 MB
    u16*   t_bf    = (u16*)  (ws + 33554432);      //  4 MB
    float* hinit   = (float*)(ws + 33554432);      //  8 MB (over t_bf, sequenced)
    u16*   u_bf    = (u16*)  (ws + 41943040);      //  8 MB
    u16*   delta_bf= (u16*)  (ws + 50331648);      //  8 MB
    float* xdbl    = (float*)(ws + 58720256);      //  2 MB
    u16*   wIn     = (u16*)  (ws + 60817408);      //  4 MB
    u16*   wXp     = (u16*)  (ws + 65011712);      //  512 KB
    u16*   wOut    = (u16*)  (ws + 65536000);      //  2 MB
    u16*   wDt     = (u16*)  (ws + 67633152);      //  128 KB
    u16*   dt_bf   = (u16*)  (ws + 67764224);      //  256 KB -> end 68,026,368

    dim3 blk(256);

    convert_weights<<<15104, blk, 0, stream>>>(conv_w, in_proj_w, x_proj_w,
                                               out_proj_w, dt_proj_w,
                                               wPatch, wIn, wXp, wOut, wDt);
    build_patches<<<12288, blk, 0, stream>>>(x, A_patch);
    gemm_bt<1><<<dim3(4, 32), blk, 0, stream>>>(A_patch, wPatch, xe, conv_b,
                                                nullptr, nullptr, MTOK, DM_, KPATCH);
    ln_kernel<false><<<1024, blk, 0, stream>>>(xe, tokens, pe_g, pe_b);

    for (int i = 0; i < 2; i++) {
        ln_kernel<true><<<1024, blk, 0, stream>>>(tokens, t_bf,
                                                  ln_g + i * DM_, ln_b + i * DM_);
        // in_proj merged: [4096 x 512] x [2048 x 512]^T; cols<1024 -> xz_bf,
        // cols>=1024 -> silu -> g_bf
        gemm_bt<5><<<dim3(16, 32), blk, 0, stream>>>(t_bf, wIn + i * 1048576,
                                                     (float*)xz_bf, nullptr, nullptr,
                                                     g_bf, MTOK, 2048, DM_);
        conv1d_silu<<<16384, blk, 0, stream>>>(xz_bf, c1d_w + i * 4096,
                                               c1d_b + i * 1024, u_bf);
        // x_proj: [4096 x 1024] x [128 x 1024]^T -> xdbl f32 (dt|B|C|pad)
        gemm_bt<0><<<dim3(1, 32), blk, 0, stream>>>(u_bf, wXp + i * 131072, xdbl,
                                                    nullptr, nullptr, nullptr,
                                                    MTOK, 128, DIN);
        extract_dt<<<512, blk, 0, stream>>>(xdbl, dt_bf);
        // delta = softplus(dt @ dpw^T + dpb) -> bf16
        gemm_bt<3><<<dim3(8, 32), blk, 0, stream>>>(dt_bf, wDt + i * 32768,
                                                    (float*)delta_bf,
                                                    dt_proj_b + i * 1024, nullptr,
                                                    nullptr, MTOK, DIN, DTR);
        scan_part1<<<dim3(4, 4, NCH), blk, 0, stream>>>(delta_bf, u_bf, xdbl,
                                                        A_log + i * 16384,
                                                        summP, summQ);
        scan_carry<<<256, blk, 0, stream>>>(summP, summQ, hinit);
        scan_part2<<<dim3(4, 4, NCH), blk, 0, stream>>>(delta_bf, u_bf, xdbl, g_bf,
                                                        A_log + i * 16384,
                                                        Dp + i * 1024, hinit, y_bf);
        // out_proj + residual: [4096 x 1024] x [512 x 1024]^T + tokens
        float* dst = (i == 1) ? (float*)d_out : tokens;
        gemm_bt<2><<<dim3(4, 32), blk, 0, stream>>>(y_bf, wOut + i * 524288, dst,
                                                    nullptr, tokens, nullptr,
                                                    MTOK, DM_, DIN);
    }
}

// Round 5
// 442.850 us; speedup vs baseline: 2.5403x; 1.1048x over previous
//
#include <hip/hip_runtime.h>

// ResidualMambaTokenStage: patch-embed conv (as GEMM) + ch-LN, then 2x
// (LN -> in_proj -> causal dwconv1d+silu -> x_proj -> dt/softplus ->
//  selective scan -> gate -> out_proj + residual).
// R5: occupancy-shaped GEMMs. 64x128-tile variant for patch/out_proj (256
// blocks), split-K 64x64 for x_proj (256 blocks + deterministic reduce),
// x_proj weights unpadded (xdbl stride 64).

#define BB   4
#define LL   1024
#define MTOK 4096
#define DM_  512
#define DIN  1024
#define DST  16
#define DTR  32
#define KPATCH 768
#define LCH  32          // scan chunk length
#define NCH  32          // chunks per sequence
#define NBDS 65536       // B * DIN * DST carry sequences

typedef unsigned short u16;
typedef __attribute__((ext_vector_type(8))) short bf16x8_t;
typedef __attribute__((ext_vector_type(4))) float floatx4_t;

__device__ inline u16 f2bf(float f) {
    unsigned int u = __float_as_uint(f);
    unsigned int r = (u + 0x7FFFu + ((u >> 16) & 1u)) >> 16;   // RNE
    return (u16)r;
}
__device__ inline float bf2f(u16 h) {
    return __uint_as_float(((unsigned int)h) << 16);
}

// ---------------------------------------------------------------- weights
__global__ __launch_bounds__(256) void convert_weights(
    const float* __restrict__ conv_w, const float* __restrict__ in_proj_w,
    const float* __restrict__ x_proj_w, const float* __restrict__ out_proj_w,
    const float* __restrict__ dt_proj_w,
    u16* __restrict__ wPatch, u16* __restrict__ wIn,
    u16* __restrict__ wXp, u16* __restrict__ wOut, u16* __restrict__ wDt)
{
    int g = blockIdx.x * 256 + threadIdx.x;
    const int N0 = 393216;            // conv_w 512*768
    const int N1 = N0 + 2097152;      // in_proj 2*2048*512
    const int N2 = N1 + 131072;       // x_proj 2*64*1024 (unpadded)
    const int N3 = N2 + 1048576;      // out_proj 2*512*1024
    const int N4 = N3 + 65536;        // dt_proj_w 2*1024*32
    if (g < N0) {
        wPatch[g] = f2bf(conv_w[g]);
    } else if (g < N1) {
        int o = g - N0; wIn[o] = f2bf(in_proj_w[o]);
    } else if (g < N2) {
        int o = g - N1; wXp[o] = f2bf(x_proj_w[o]);
    } else if (g < N3) {
        int o = g - N2; wOut[o] = f2bf(out_proj_w[o]);
    } else if (g < N4) {
        int o = g - N3; wDt[o] = f2bf(dt_proj_w[o]);
    }
}

// ------------------------------------------------------------- patch im2col
__global__ __launch_bounds__(256) void build_patches(
    const float* __restrict__ x, u16* __restrict__ Ap)
{
    int g = blockIdx.x * 256 + threadIdx.x;
    int m = g / KPATCH, k = g % KPATCH;
    int b = m >> 10, l = m & 1023, hp = l >> 5, wp = l & 31;
    int c = k >> 8, rem = k & 255, py = rem >> 4, px = rem & 15;
    float v = x[(((size_t)(b * 3 + c)) * 512 + hp * 16 + py) * 512 + wp * 16 + px];
    Ap[g] = f2bf(v);
}

// ------------------------------------------------------- GEMM 128x128 tile
// C[M][N] = A[M][K] * Bt[N][K]^T, bf16 in, global_load_lds staging.
// EPI: 0 f32, 3 softplus(v+bias)->bf16, 5 dual (col<1024 bf16 C, else silu->aux).
template<int EPI>
__global__ __launch_bounds__(256, 2) void gemm_bt(
    const u16* __restrict__ A, const u16* __restrict__ Bt,
    float* __restrict__ C, const float* __restrict__ bias,
    const float* __restrict__ res, u16* __restrict__ aux,
    int M, int N, int K)
{
    __shared__ short As[128 * 32];
    __shared__ short Bs[128 * 32];
    const int tid  = threadIdx.x;
    const int lane = tid & 63;
    const int wv   = tid >> 6;
    const int quad = lane >> 4;
    const int l16  = lane & 15;
    const int wm = wv >> 1, wn = wv & 1;
    const int m0 = blockIdx.y * 128, n0 = blockIdx.x * 128;

    floatx4_t acc[4][4] = {};

    const int srow = wv * 16 + (lane >> 2);
    const int scol = (lane & 3) * 8;

    for (int kk = 0; kk < K; kk += 32) {
        __builtin_amdgcn_global_load_lds(
            (const __attribute__((address_space(1))) unsigned int*)
                (A + (size_t)(m0 + srow) * K + kk + scol),
            (__attribute__((address_space(3))) unsigned int*)(As + wv * 16 * 32),
            16, 0, 0);
        __builtin_amdgcn_global_load_lds(
            (const __attribute__((address_space(1))) unsigned int*)
                (A + (size_t)(m0 + 64 + srow) * K + kk + scol),
            (__attribute__((address_space(3))) unsigned int*)(As + (64 + wv * 16) * 32),
            16, 0, 0);
        __builtin_amdgcn_global_load_lds(
            (const __attribute__((address_space(1))) unsigned int*)
                (Bt + (size_t)(n0 + srow) * K + kk + scol),
            (__attribute__((address_space(3))) unsigned int*)(Bs + wv * 16 * 32),
            16, 0, 0);
        __builtin_amdgcn_global_load_lds(
            (const __attribute__((address_space(1))) unsigned int*)
                (Bt + (size_t)(n0 + 64 + srow) * K + kk + scol),
            (__attribute__((address_space(3))) unsigned int*)(Bs + (64 + wv * 16) * 32),
            16, 0, 0);
        __syncthreads();
        bf16x8_t af[4], bfr[4];
#pragma unroll
        for (int t = 0; t < 4; t++)
            af[t] = *(const bf16x8_t*)&As[(wm * 64 + t * 16 + l16) * 32 + quad * 8];
#pragma unroll
        for (int t = 0; t < 4; t++)
            bfr[t] = *(const bf16x8_t*)&Bs[(wn * 64 + t * 16 + l16) * 32 + quad * 8];
#pragma unroll
        for (int tm = 0; tm < 4; tm++)
#pragma unroll
            for (int tn = 0; tn < 4; tn++)
                acc[tm][tn] = __builtin_amdgcn_mfma_f32_16x16x32_bf16(
                    af[tm], bfr[tn], acc[tm][tn], 0, 0, 0);
        __syncthreads();
    }
#pragma unroll
    for (int tm = 0; tm < 4; tm++) {
#pragma unroll
        for (int r = 0; r < 4; r++) {
            int gr = m0 + wm * 64 + tm * 16 + quad * 4 + r;
#pragma unroll
            for (int tn = 0; tn < 4; tn++) {
                int gc = n0 + wn * 64 + tn * 16 + l16;
                float v = acc[tm][tn][r];
                if (EPI == 3) {
                    v += bias[gc];
                    v = (v > 20.f) ? v : log1pf(__expf(v));
                    ((u16*)C)[(size_t)gr * N + gc] = f2bf(v);
                } else if (EPI == 5) {
                    if (gc < 1024) {
                        ((u16*)C)[(size_t)gr * 1024 + gc] = f2bf(v);
                    } else {
                        float sv = v / (1.f + __expf(-v));
                        aux[(size_t)gr * 1024 + gc - 1024] = f2bf(sv);
                    }
                } else {
                    C[(size_t)gr * N + gc] = v;
                }
            }
        }
    }
}

// -------------------------------------------------------- GEMM 64x128 tile
// 4 waves, each 32x64 (2 m-frags x 4 n-frags). EPI: 1 +bias f32, 2 +res f32.
template<int EPI>
__global__ __launch_bounds__(256, 2) void gemm_bt64(
    const u16* __restrict__ A, const u16* __restrict__ Bt,
    float* __restrict__ C, const float* __restrict__ bias,
    const float* __restrict__ res, int M, int N, int K)
{
    __shared__ short As[64 * 32];
    __shared__ short Bs[128 * 32];
    const int tid  = threadIdx.x;
    const int lane = tid & 63;
    const int wv   = tid >> 6;
    const int quad = lane >> 4;
    const int l16  = lane & 15;
    const int wm = wv >> 1, wn = wv & 1;
    const int m0 = blockIdx.y * 64, n0 = blockIdx.x * 128;

    floatx4_t acc[2][4] = {};

    const int srow = wv * 16 + (lane >> 2);
    const int scol = (lane & 3) * 8;

    for (int kk = 0; kk < K; kk += 32) {
        __builtin_amdgcn_global_load_lds(
            (const __attribute__((address_space(1))) unsigned int*)
                (A + (size_t)(m0 + srow) * K + kk + scol),
            (__attribute__((address_space(3))) unsigned int*)(As + wv * 16 * 32),
            16, 0, 0);
        __builtin_amdgcn_global_load_lds(
            (const __attribute__((address_space(1))) unsigned int*)
                (Bt + (size_t)(n0 + srow) * K + kk + scol),
            (__attribute__((address_space(3))) unsigned int*)(Bs + wv * 16 * 32),
            16, 0, 0);
        __builtin_amdgcn_global_load_lds(
            (const __attribute__((address_space(1))) unsigned int*)
                (Bt + (size_t)(n0 + 64 + srow) * K + kk + scol),
            (__attribute__((address_space(3))) unsigned int*)(Bs + (64 + wv * 16) * 32),
            16, 0, 0);
        __syncthreads();
        bf16x8_t af[2], bfr[4];
#pragma unroll
        for (int t = 0; t < 2; t++)
            af[t] = *(const bf16x8_t*)&As[(wm * 32 + t * 16 + l16) * 32 + quad * 8];
#pragma unroll
        for (int t = 0; t < 4; t++)
            bfr[t] = *(const bf16x8_t*)&Bs[(wn * 64 + t * 16 + l16) * 32 + quad * 8];
#pragma unroll
        for (int tm = 0; tm < 2; tm++)
#pragma unroll
            for (int tn = 0; tn < 4; tn++)
                acc[tm][tn] = __builtin_amdgcn_mfma_f32_16x16x32_bf16(
                    af[tm], bfr[tn], acc[tm][tn], 0, 0, 0);
        __syncthreads();
    }
#pragma unroll
    for (int tm = 0; tm < 2; tm++) {
#pragma unroll
        for (int r = 0; r < 4; r++) {
            int gr = m0 + wm * 32 + tm * 16 + quad * 4 + r;
#pragma unroll
            for (int tn = 0; tn < 4; tn++) {
                int gc = n0 + wn * 64 + tn * 16 + l16;
                float v = acc[tm][tn][r];
                if (EPI == 1) v += bias[gc];
                if (EPI == 2) v += res[(size_t)gr * N + gc];
                C[(size_t)gr * N + gc] = v;
            }
        }
    }
}

// ----------------------------------------------- GEMM 64x64 split-K (x_proj)
// N fixed 64. Grid (1, M/64, KS). Writes f32 partials part[kz][M][64].
__global__ __launch_bounds__(256, 2) void gemm_sk(
    const u16* __restrict__ A, const u16* __restrict__ Bt,
    float* __restrict__ part, int M, int K, int KC)
{
    __shared__ short As[64 * 32];
    __shared__ short Bs[64 * 32];
    const int tid  = threadIdx.x;
    const int lane = tid & 63;
    const int wv   = tid >> 6;
    const int quad = lane >> 4;
    const int l16  = lane & 15;
    const int m0 = blockIdx.y * 64;
    const int kz = blockIdx.z;

    floatx4_t acc[4] = {};

    const int srow = wv * 16 + (lane >> 2);
    const int scol = (lane & 3) * 8;
    const int k0 = kz * KC;

    for (int kk = k0; kk < k0 + KC; kk += 32) {
        __builtin_amdgcn_global_load_lds(
            (const __attribute__((address_space(1))) unsigned int*)
                (A + (size_t)(m0 + srow) * K + kk + scol),
            (__attribute__((address_space(3))) unsigned int*)(As + wv * 16 * 32),
            16, 0, 0);
        __builtin_amdgcn_global_load_lds(
            (const __attribute__((address_space(1))) unsigned int*)
                (Bt + (size_t)srow * K + kk + scol),
            (__attribute__((address_space(3))) unsigned int*)(Bs + wv * 16 * 32),
            16, 0, 0);
        __syncthreads();
        bf16x8_t af, bfr[4];
        af = *(const bf16x8_t*)&As[(wv * 16 + l16) * 32 + quad * 8];
#pragma unroll
        for (int t = 0; t < 4; t++)
            bfr[t] = *(const bf16x8_t*)&Bs[(t * 16 + l16) * 32 + quad * 8];
#pragma unroll
        for (int tn = 0; tn < 4; tn++)
            acc[tn] = __builtin_amdgcn_mfma_f32_16x16x32_bf16(af, bfr[tn], acc[tn], 0, 0, 0);
        __syncthreads();
    }
#pragma unroll
    for (int r = 0; r < 4; r++) {
        int gr = m0 + wv * 16 + quad * 4 + r;
#pragma unroll
        for (int tn = 0; tn < 4; tn++)
            part[((size_t)kz * MTOK + gr) * 64 + tn * 16 + l16] = acc[tn][r];
    }
}

// ------------------------------------- split-K reduce + dt extraction (bf16)
__global__ __launch_bounds__(256) void reduce_xdbl(
    const float* __restrict__ part, float* __restrict__ xdbl,
    u16* __restrict__ dt_bf)
{
    int g = blockIdx.x * 256 + threadIdx.x;      // 4096*64
    float v = part[g] + part[g + MTOK * 64] + part[g + 2 * MTOK * 64]
            + part[g + 3 * MTOK * 64];
    xdbl[g] = v;
    int c = g & 63;
    if (c < 32) dt_bf[(g >> 6) * 32 + c] = f2bf(v);
}

// --------------------------------------------------------------------- LN
template<bool BF16OUT>
__global__ __launch_bounds__(256) void ln_kernel(
    const float* __restrict__ in, void* __restrict__ out,
    const float* __restrict__ g, const float* __restrict__ b)
{
    int token = blockIdx.x * 4 + (threadIdx.x >> 6);
    int lane  = threadIdx.x & 63;
    const float* row = in + (size_t)token * DM_;
    float v[8], s = 0.f, q = 0.f;
#pragma unroll
    for (int j = 0; j < 8; j++) {
        v[j] = row[lane + j * 64];
        s += v[j]; q = fmaf(v[j], v[j], q);
    }
#pragma unroll
    for (int off = 32; off >= 1; off >>= 1) {
        s += __shfl_xor(s, off);
        q += __shfl_xor(q, off);
    }
    float mean = s * (1.f / DM_);
    float var  = q * (1.f / DM_) - mean * mean;
    float inv  = rsqrtf(var + 1e-5f);
#pragma unroll
    for (int j = 0; j < 8; j++) {
        int idx = lane + j * 64;
        float o = (v[j] - mean) * inv * g[idx] + b[idx];
        if (BF16OUT) ((u16*)out)[(size_t)token * DM_ + idx] = f2bf(o);
        else         ((float*)out)[(size_t)token * DM_ + idx] = o;
    }
}

// ----------------------------------------------------- causal dwconv1d+silu
__global__ __launch_bounds__(256) void conv1d_silu(
    const u16* __restrict__ xz_bf, const float* __restrict__ w,
    const float* __restrict__ cb, u16* __restrict__ u_bf)
{
    int g = blockIdx.x * 256 + threadIdx.x;      // 4096*1024
    int d = g & 1023, m = g >> 10, l = m & 1023;
    float acc = cb[d];
#pragma unroll
    for (int j = 0; j < 4; j++) {
        int lj = l + j - 3;
        if (lj >= 0)
            acc = fmaf(bf2f(xz_bf[(size_t)(m + j - 3) * 1024 + d]), w[d * 4 + j], acc);
    }
    float uu = acc / (1.f + __expf(-acc));
    u_bf[g] = f2bf(uu);
}

// ------------------------------------------------- chunk-parallel scan: P1
// Thread owns (b, d, chunk), all 16 states in registers.
__global__ __launch_bounds__(256) void scan_part1(
    const u16* __restrict__ delta_bf, const u16* __restrict__ u_bf,
    const float* __restrict__ xdbl, const float* __restrict__ alog,
    float* __restrict__ summP, float* __restrict__ summQ)
{
    __shared__ float sB[LCH][16];
    const int tid = threadIdx.x;
    const int d  = blockIdx.x * 256 + tid;
    const int b  = blockIdx.y, ch = blockIdx.z;
    const int m0 = b * LL + ch * LCH;

    for (int e = tid; e < LCH * 16; e += 256) {
        int li = e >> 4, s = e & 15;
        sB[li][s] = xdbl[(size_t)(m0 + li) * 64 + 32 + s];
    }
    float aneg[16];
#pragma unroll
    for (int s = 0; s < 16; s++) aneg[s] = -__expf(alog[d * 16 + s]);
    __syncthreads();

    float Q[16] = {};
    float dsum = 0.f;
#pragma unroll 4
    for (int j = 0; j < LCH; j++) {
        float dl = bf2f(delta_bf[(size_t)(m0 + j) * 1024 + d]);
        float du = dl * bf2f(u_bf[(size_t)(m0 + j) * 1024 + d]);
        dsum += dl;
#pragma unroll
        for (int s = 0; s < 16; s++) {
            float a = __expf(dl * aneg[s]);
            Q[s] = fmaf(a, Q[s], sB[j][s] * du);
        }
    }
    size_t base = (size_t)ch * NBDS + ((size_t)b * 1024 + d) * 16;
#pragma unroll
    for (int s = 0; s < 16; s++) {
        summP[base + s] = __expf(dsum * aneg[s]);
        summQ[base + s] = Q[s];
    }
}

// ------------------------------------------------- carry scan over chunks
__global__ __launch_bounds__(256) void scan_carry(
    const float* __restrict__ summP, const float* __restrict__ summQ,
    float* __restrict__ hinit)
{
    int bds = blockIdx.x * 256 + threadIdx.x;    // 65536
    float h = 0.f;
#pragma unroll
    for (int c = 0; c < NCH; c++) {
        hinit[(size_t)c * NBDS + bds] = h;
        h = fmaf(summP[(size_t)c * NBDS + bds], h, summQ[(size_t)c * NBDS + bds]);
    }
}

// ------------------------------------------------- chunk-parallel scan: P2
__global__ __launch_bounds__(256) void scan_part2(
    const u16* __restrict__ delta_bf, const u16* __restrict__ u_bf,
    const float* __restrict__ xdbl, const u16* __restrict__ g_bf,
    const float* __restrict__ alog, const float* __restrict__ Dp,
    const float* __restrict__ hinit, u16* __restrict__ y_bf)
{
    __shared__ float sB[LCH][16];
    __shared__ float sC[LCH][16];
    const int tid = threadIdx.x;
    const int d  = blockIdx.x * 256 + tid;
    const int b  = blockIdx.y, ch = blockIdx.z;
    const int m0 = b * LL + ch * LCH;

    for (int e = tid; e < LCH * 16; e += 256) {
        int li = e >> 4, s = e & 15;
        sB[li][s] = xdbl[(size_t)(m0 + li) * 64 + 32 + s];
        sC[li][s] = xdbl[(size_t)(m0 + li) * 64 + 48 + s];
    }
    float aneg[16];
#pragma unroll
    for (int s = 0; s < 16; s++) aneg[s] = -__expf(alog[d * 16 + s]);
    const float dp = Dp[d];
    float h[16];
    size_t hbase = (size_t)ch * NBDS + ((size_t)b * 1024 + d) * 16;
#pragma unroll
    for (int s = 0; s < 16; s++) h[s] = hinit[hbase + s];
    __syncthreads();

#pragma unroll 4
    for (int j = 0; j < LCH; j++) {
        size_t m = (size_t)(m0 + j) * 1024 + d;
        float dl = bf2f(delta_bf[m]);
        float uu = bf2f(u_bf[m]);
        float gg = bf2f(g_bf[m]);
        float du = dl * uu;
        float y = 0.f;
#pragma unroll
        for (int s = 0; s < 16; s++) {
            float a = __expf(dl * aneg[s]);
            h[s] = fmaf(a, h[s], sB[j][s] * du);
            y = fmaf(h[s], sC[j][s], y);
        }
        y_bf[m] = f2bf(fmaf(uu, dp, y) * gg);
    }
}

// ---------------------------------------------------------------- launcher
extern "C" void kernel_launch(void* const* d_in, const int* in_sizes, int n_in,
                              void* d_out, int out_size, void* d_ws, size_t ws_size,
                              hipStream_t stream)
{
    const float* x         = (const float*)d_in[0];
    const float* conv_w    = (const float*)d_in[1];
    const float* conv_b    = (const float*)d_in[2];
    const float* pe_g      = (const float*)d_in[3];
    const float* pe_b      = (const float*)d_in[4];
    const float* ln_g      = (const float*)d_in[5];
    const float* ln_b      = (const float*)d_in[6];
    const float* in_proj_w = (const float*)d_in[7];
    const float* c1d_w     = (const float*)d_in[8];
    const float* c1d_b     = (const float*)d_in[9];
    const float* x_proj_w  = (const float*)d_in[10];
    const float* dt_proj_w = (const float*)d_in[11];
    const float* dt_proj_b = (const float*)d_in[12];
    const float* A_log     = (const float*)d_in[13];
    const float* Dp        = (const float*)d_in[14];
    const float* out_proj_w= (const float*)d_in[15];

    char* ws = (char*)d_ws;
    // ws layout (~71 MB). Slab @0 (16MB) time-multiplexed:
    //   phase1: A_patch(6MB)+xe(8MB); per-iter: xz_bf(8MB, dead after conv1d)
    //   -> summP(8)+summQ(8) -> y_bf(8, over summP after carry).
    u16*   A_patch = (u16*)  (ws + 0);
    float* xe      = (float*)(ws + 6291456);
    u16*   xz_bf   = (u16*)  (ws + 0);
    float* summP   = (float*)(ws + 0);
    float* summQ   = (float*)(ws + 8388608);
    u16*   y_bf    = (u16*)  (ws + 0);
    u16*   g_bf    = (u16*)  (ws + 16777216);      //  8 MB (phase1: wPatch)
    u16*   wPatch  = (u16*)  (ws + 16777216);
    float* tokens  = (float*)(ws + 25165824);      //  8 MB
    u16*   t_bf    = (u16*)  (ws + 33554432);      //  4 MB
    float* hinit   = (float*)(ws + 33554432);      //  8 MB (over t_bf, sequenced)
    u16*   u_bf    = (u16*)  (ws + 41943040);      //  8 MB
    u16*   delta_bf= (u16*)  (ws + 50331648);      //  8 MB
    float* xdbl    = (float*)(ws + 58720256);      //  1 MB [4096][64]
    float* xdblp   = (float*)(ws + 59768832);      //  4 MB split-K partials
    u16*   wIn     = (u16*)  (ws + 63963136);      //  4 MB
    u16*   wXp     = (u16*)  (ws + 68157440);      //  256 KB
    u16*   wOut    = (u16*)  (ws + 68419584);      //  2 MB
    u16*   wDt     = (u16*)  (ws + 70516736);      //  128 KB
    u16*   dt_bf   = (u16*)  (ws + 70647808);      //  256 KB -> end 70,910,976

    dim3 blk(256);

    convert_weights<<<14592, blk, 0, stream>>>(conv_w, in_proj_w, x_proj_w,
                                               out_proj_w, dt_proj_w,
                                               wPatch, wIn, wXp, wOut, wDt);
    build_patches<<<12288, blk, 0, stream>>>(x, A_patch);
    // patch-embed: [4096 x 768] x [512 x 768]^T + conv bias (64x128 tiles)
    gemm_bt64<1><<<dim3(4, 64), blk, 0, stream>>>(A_patch, wPatch, xe, conv_b,
                                                  nullptr, MTOK, DM_, KPATCH);
    ln_kernel<false><<<1024, blk, 0, stream>>>(xe, tokens, pe_g, pe_b);

    for (int i = 0; i < 2; i++) {
        ln_kernel<true><<<1024, blk, 0, stream>>>(tokens, t_bf,
                                                  ln_g + i * DM_, ln_b + i * DM_);
        // in_proj merged: [4096 x 512] x [2048 x 512]^T; cols<1024 -> xz_bf,
        // cols>=1024 -> silu -> g_bf
        gemm_bt<5><<<dim3(16, 32), blk, 0, stream>>>(t_bf, wIn + i * 1048576,
                                                     (float*)xz_bf, nullptr, nullptr,
                                                     g_bf, MTOK, 2048, DM_);
        conv1d_silu<<<16384, blk, 0, stream>>>(xz_bf, c1d_w + i * 4096,
                                               c1d_b + i * 1024, u_bf);
        // x_proj split-K: [4096 x 1024] x [64 x 1024]^T -> 4 partials
        gemm_sk<<<dim3(1, 64, 4), blk, 0, stream>>>(u_bf, wXp + i * 65536, xdblp,
                                                    MTOK, DIN, 256);
        reduce_xdbl<<<1024, blk, 0, stream>>>(xdblp, xdbl, dt_bf);
        // delta = softplus(dt @ dpw^T + dpb) -> bf16
        gemm_bt<3><<<dim3(8, 32), blk, 0, stream>>>(dt_bf, wDt + i * 32768,
                                                    (float*)delta_bf,
                                                    dt_proj_b + i * 1024, nullptr,
                                                    nullptr, MTOK, DIN, DTR);
        scan_part1<<<dim3(4, 4, NCH), blk, 0, stream>>>(delta_bf, u_bf, xdbl,
                                                        A_log + i * 16384,
                                                        summP, summQ);
        scan_carry<<<256, blk, 0, stream>>>(summP, summQ, hinit);
        scan_part2<<<dim3(4, 4, NCH), blk, 0, stream>>>(delta_bf, u_bf, xdbl, g_bf,
                                                        A_log + i * 16384,
                                                        Dp + i * 1024, hinit, y_bf);
        // out_proj + residual: [4096 x 1024] x [512 x 1024]^T + tokens (64x128)
        float* dst = (i == 1) ? (float*)d_out : tokens;
        gemm_bt64<2><<<dim3(4, 64), blk, 0, stream>>>(y_bf, wOut + i * 524288, dst,
                                                      nullptr, tokens, MTOK, DM_, DIN);
    }
}